// Round 8
// baseline (384.851 us; speedup 1.0000x reference)
//
#include <hip/hip_runtime.h>
#include <hip/hip_bf16.h>

#define N_NODES 50000
#define N_EDGES 1600000
#define IN_FEATS 512
#define N_HIDDEN 128
#define N_CLASSES 40
#define NBKT 782      // ceil(50000/64) buckets of 64 nodes
#define NBLK 800      // partition blocks
#define EPB 2000      // edges per partition block (800*2000 = 1.6M exact)

typedef __attribute__((ext_vector_type(8))) short bf16x8;
typedef __attribute__((ext_vector_type(4))) float f32x4;

__device__ __forceinline__ unsigned short f2bf(float f) {
    unsigned u = __float_as_uint(f);
    u = (u + 0x7FFFu + ((u >> 16) & 1u)) >> 16;   // round-to-nearest-even
    return (unsigned short)u;
}
__device__ __forceinline__ float bf2f(unsigned short h) {
    return __uint_as_float(((unsigned)h) << 16);
}
// packed f32x2 -> bf16x2 (RTNE), lowers to v_cvt_pk_bf16_f32 on gfx950
__device__ __forceinline__ unsigned pk_bf(float a, float b) {
    __hip_bfloat162 h = __float22bfloat162_rn(make_float2(a, b));
    union { __hip_bfloat162 v; unsigned u; } c;
    c.v = h;
    return c.u;   // low 16 = bf(a), high 16 = bf(b)
}

// 8 floats (two float4) -> hi/lo bf16x8 fragments, in registers.
__device__ __forceinline__ void cvt8(float4 a, float4 b, bf16x8& h, bf16x8& l) {
    unsigned h0 = pk_bf(a.x, a.y), h1 = pk_bf(a.z, a.w);
    unsigned h2 = pk_bf(b.x, b.y), h3 = pk_bf(b.z, b.w);
    unsigned l0 = pk_bf(a.x - __uint_as_float(h0 << 16),
                        a.y - __uint_as_float(h0 & 0xffff0000u));
    unsigned l1 = pk_bf(a.z - __uint_as_float(h1 << 16),
                        a.w - __uint_as_float(h1 & 0xffff0000u));
    unsigned l2 = pk_bf(b.x - __uint_as_float(h2 << 16),
                        b.y - __uint_as_float(h2 & 0xffff0000u));
    unsigned l3 = pk_bf(b.z - __uint_as_float(h3 << 16),
                        b.w - __uint_as_float(h3 & 0xffff0000u));
    union U { unsigned u[4]; bf16x8 v; };
    U H; H.u[0] = h0; H.u[1] = h1; H.u[2] = h2; H.u[3] = h3; h = H.v;
    U L; L.u[0] = l0; L.u[1] = l1; L.u[2] = l2; L.u[3] = l3; l = L.v;
}

__device__ __forceinline__ int imin(int a, int b) { return a < b ? a : b; }

// ---------------------------------------------------------------------------
// setup: W1 -> k-chunked bf16 hi/lo [kc][col][ki]; W2 -> f32 transposed
// [40][128] (consumed by agg1's fused gemm2 epilogue).
__global__ __launch_bounds__(256) void setup_cvt(
    const float* __restrict__ W1, const float* __restrict__ W2,
    unsigned short* __restrict__ W1ch, unsigned short* __restrict__ W1cl,
    float* __restrict__ W2tf) {
    int i = blockIdx.x * 256 + threadIdx.x;
    if (i < IN_FEATS * N_HIDDEN) {
        int k = i >> 7, c = i & 127;
        float v = W1[i];
        unsigned short h = f2bf(v);
        int o = (k >> 5) * 4096 + c * 32 + (k & 31);
        W1ch[o] = h;
        W1cl[o] = f2bf(v - bf2f(h));
    } else {
        int j = i - IN_FEATS * N_HIDDEN;    // 0..5119 (grid sized exactly)
        int c = j >> 7, k = j & 127;
        W2tf[j] = W2[k * N_CLASSES + c];
    }
}

// ---------------------------------------------------------------------------
// megaA: blocks [0,NBKT) = gemm1 tiles; blocks [NBKT,NBKT+NBLK) = p1_hist.
// gemm1 r7 structure (60us plateau, closed): lane-linear LDS, two chunks per
// barrier, 4 LDS buffers.

#define MFJ(AH, AL, BH, BL, ACC)                                              \
    ACC = __builtin_amdgcn_mfma_f32_16x16x32_bf16(AH, BH, ACC, 0, 0, 0);      \
    ACC = __builtin_amdgcn_mfma_f32_16x16x32_bf16(AH, BL, ACC, 0, 0, 0);      \
    ACC = __builtin_amdgcn_mfma_f32_16x16x32_bf16(AL, BH, ACC, 0, 0, 0);

#define CHUNK_COMPUTE(FRAGBASE, KC)                                           \
    {                                                                         \
        const unsigned short* wk  = wbh + (KC) * 4096;                        \
        const unsigned short* wkl = wbl + (KC) * 4096;                        \
        bf16x8 bh0 = *(const bf16x8*)(wk);                                    \
        bf16x8 bh1 = *(const bf16x8*)(wk + 512);                              \
        bf16x8 bl0 = *(const bf16x8*)(wkl);                                   \
        bf16x8 bl1 = *(const bf16x8*)(wkl + 512);                             \
        const unsigned short* fb = (FRAGBASE);                                \
        bf16x8 ah0 = *(const bf16x8*)(fb + (0 * 64 + lane) * 8);              \
        bf16x8 ah1 = *(const bf16x8*)(fb + (1 * 64 + lane) * 8);              \
        bf16x8 ah2 = *(const bf16x8*)(fb + (2 * 64 + lane) * 8);              \
        bf16x8 ah3 = *(const bf16x8*)(fb + (3 * 64 + lane) * 8);              \
        bf16x8 al0 = *(const bf16x8*)(fb + 2048 + (0 * 64 + lane) * 8);       \
        bf16x8 al1 = *(const bf16x8*)(fb + 2048 + (1 * 64 + lane) * 8);       \
        bf16x8 al2 = *(const bf16x8*)(fb + 2048 + (2 * 64 + lane) * 8);       \
        bf16x8 al3 = *(const bf16x8*)(fb + 2048 + (3 * 64 + lane) * 8);       \
        MFJ(ah0, al0, bh0, bl0, acc[0][0]) MFJ(ah0, al0, bh1, bl1, acc[0][1]) \
        MFJ(ah1, al1, bh0, bl0, acc[1][0]) MFJ(ah1, al1, bh1, bl1, acc[1][1]) \
        MFJ(ah2, al2, bh0, bl0, acc[2][0]) MFJ(ah2, al2, bh1, bl1, acc[2][1]) \
        MFJ(ah3, al3, bh0, bl0, acc[3][0]) MFJ(ah3, al3, bh1, bl1, acc[3][1]) \
    }

__global__ __launch_bounds__(256) void megaA(
    const int* __restrict__ src, const int* __restrict__ dst,
    int* __restrict__ histD, int* __restrict__ histS,
    const float* __restrict__ X, const unsigned short* __restrict__ Wch,
    const unsigned short* __restrict__ Wcl, unsigned short* __restrict__ Hb) {
    __shared__ __align__(16) unsigned char smem[32768];
    const int tid = threadIdx.x;

    if (blockIdx.x >= NBKT) {
        // ---- p1_hist ----
        int* hd = (int*)smem;
        int* hs = hd + NBKT;
        int b = blockIdx.x - NBKT;
        for (int i = tid; i < NBKT; i += 256) { hd[i] = 0; hs[i] = 0; }
        __syncthreads();
        int e0 = b * EPB;
        for (int i = tid; i < EPB; i += 256) {
            atomicAdd(&hd[dst[e0 + i] >> 6], 1);
            atomicAdd(&hs[src[e0 + i] >> 6], 1);
        }
        __syncthreads();
        for (int i = tid; i < NBKT; i += 256) {
            histD[b * NBKT + i] = hd[i];
            histS[b * NBKT + i] = hs[i];
        }
        return;
    }
    // ---- gemm1: 64 rows, split-precision bf16 MFMA, unscaled output ----
    typedef unsigned short ush;
    ush* lds = (ush*)smem;   // set s at + s*8192 ush; within set:
                             // chunkA hi +0, lo +2048; chunkB hi +4096, lo +6144

    const int lane = tid & 63;
    const int wv = tid >> 6;
    const int m = lane & 15;
    const int q = lane >> 4;
    const int q8 = q * 8;
    const int row0 = blockIdx.x * 64;

    const unsigned short* wbh = Wch + (wv * 32 + m) * 32 + q8;
    const unsigned short* wbl = Wcl + (wv * 32 + m) * 32 + q8;

    const int srow = (tid >> 6) * 16 + (tid & 15);      // row within tile
    const int sq8  = ((tid >> 4) & 3) * 8;              // col group * 8
    const float* xp = &X[(size_t)imin(row0 + srow, N_NODES - 1) * IN_FEATS + sq8];

    f32x4 acc[4][2];
#pragma unroll
    for (int i = 0; i < 4; i++)
#pragma unroll
        for (int j = 0; j < 2; j++) acc[i][j] = (f32x4){0.f, 0.f, 0.f, 0.f};

    // prologue: stage pair 0 (chunks 0,1) into set 0; pair 1 X into regs
    {
        float4 c00 = *(const float4*)(xp),      c01 = *(const float4*)(xp + 4);
        float4 c10 = *(const float4*)(xp + 32), c11 = *(const float4*)(xp + 36);
        bf16x8 h, l;
        cvt8(c00, c01, h, l);
        *(bf16x8*)(lds + tid * 8) = h;
        *(bf16x8*)(lds + 2048 + tid * 8) = l;
        cvt8(c10, c11, h, l);
        *(bf16x8*)(lds + 4096 + tid * 8) = h;
        *(bf16x8*)(lds + 6144 + tid * 8) = l;
    }
    float4 a00 = *(const float4*)(xp + 64), a01 = *(const float4*)(xp + 68);
    float4 a10 = *(const float4*)(xp + 96), a11 = *(const float4*)(xp + 100);
    __syncthreads();

    for (int pp = 0; pp < 8; pp++) {
        if (pp < 7) {
            ush* bs = lds + ((pp + 1) & 1) * 8192;
            bf16x8 h, l;
            cvt8(a00, a01, h, l);
            *(bf16x8*)(bs + tid * 8) = h;
            *(bf16x8*)(bs + 2048 + tid * 8) = l;
            cvt8(a10, a11, h, l);
            *(bf16x8*)(bs + 4096 + tid * 8) = h;
            *(bf16x8*)(bs + 6144 + tid * 8) = l;
        }
        if (pp < 6) {
            const float* xq = xp + (pp + 2) * 64;
            a00 = *(const float4*)(xq);      a01 = *(const float4*)(xq + 4);
            a10 = *(const float4*)(xq + 32); a11 = *(const float4*)(xq + 36);
        }
        const ush* br = lds + (pp & 1) * 8192;
        CHUNK_COMPUTE(br,        2 * pp)
        CHUNK_COMPUTE(br + 4096, 2 * pp + 1)
        if (pp < 7) __syncthreads();
    }

#pragma unroll
    for (int i = 0; i < 4; i++) {
#pragma unroll
        for (int r = 0; r < 4; r++) {
            int grow = row0 + i * 16 + q * 4 + r;
            if (grow < N_NODES) {
#pragma unroll
                for (int j = 0; j < 2; j++)
                    Hb[(size_t)grow * N_HIDDEN + wv * 32 + j * 16 + m] = f2bf(acc[i][j][r]);
            }
        }
    }
}

// ---------------------------------------------------------------------------
// P2a: one wave per bucket — parallel scan over the 800-block dimension.
__global__ __launch_bounds__(256) void p2_local(
    const int* __restrict__ histD, const int* __restrict__ histS,
    int* __restrict__ baseD, int* __restrict__ baseS,
    int* __restrict__ totD, int* __restrict__ totS) {
    int wv = threadIdx.x >> 6, lane = threadIdx.x & 63;
    int w = blockIdx.x * 4 + wv;
    if (w >= NBKT) return;
    int runD = 0, runS = 0;
#pragma unroll
    for (int c = 0; c < 13; c++) {
        int blk = c * 64 + lane;
        int vD = 0, vS = 0;
        if (blk < NBLK) {
            vD = histD[blk * NBKT + w];
            vS = histS[blk * NBKT + w];
        }
        int iD = vD, iS = vS;
#pragma unroll
        for (int off = 1; off < 64; off <<= 1) {
            int tD = __shfl_up(iD, off);
            int tS = __shfl_up(iS, off);
            if (lane >= off) { iD += tD; iS += tS; }
        }
        if (blk < NBLK) {
            baseD[blk * NBKT + w] = runD + iD - vD;
            baseS[blk * NBKT + w] = runS + iS - vS;
        }
        runD += __shfl(iD, 63);
        runS += __shfl(iS, 63);
    }
    if (lane == 0) { totD[w] = runD; totS[w] = runS; }
}

// P2b: single-block scan over the 782 bucket totals only.
__global__ __launch_bounds__(1024) void p2_small(
    const int* __restrict__ totD, const int* __restrict__ totS,
    int* __restrict__ bucket_base, int* __restrict__ srcb_base,
    int* __restrict__ offsets) {
    __shared__ int part[1024];
    int t = threadIdx.x;
    int v = (t < NBKT) ? totD[t] : 0;
    part[t] = v;
    __syncthreads();
    for (int off = 1; off < 1024; off <<= 1) {
        int x = (t >= off) ? part[t - off] : 0;
        __syncthreads();
        part[t] += x;
        __syncthreads();
    }
    if (t < NBKT) bucket_base[t] = part[t] - v;
    if (t == 0) { bucket_base[NBKT] = N_EDGES; offsets[N_NODES] = N_EDGES; }
    __syncthreads();
    v = (t < NBKT) ? totS[t] : 0;
    part[t] = v;
    __syncthreads();
    for (int off = 1; off < 1024; off <<= 1) {
        int x = (t >= off) ? part[t - off] : 0;
        __syncthreads();
        part[t] += x;
        __syncthreads();
    }
    if (t < NBKT) srcb_base[t] = part[t] - v;
    if (t == 0) srcb_base[NBKT] = N_EDGES;
}

// ---------------------------------------------------------------------------
// P3: scatter edges into bucket-partitioned arrays via LDS cursors.
__global__ __launch_bounds__(256) void p3_scatter(
    const int* __restrict__ src, const int* __restrict__ dst,
    const int* __restrict__ baseD, const int* __restrict__ baseS,
    const int* __restrict__ bucket_base, const int* __restrict__ srcb_base,
    unsigned int* __restrict__ edata, unsigned char* __restrict__ srcv) {
    __shared__ int curD[NBKT], curS[NBKT];
    int t = threadIdx.x, b = blockIdx.x;
    for (int i = t; i < NBKT; i += 256) {
        curD[i] = bucket_base[i] + baseD[b * NBKT + i];
        curS[i] = srcb_base[i] + baseS[b * NBKT + i];
    }
    __syncthreads();
    int e0 = b * EPB;
    for (int i = t; i < EPB; i += 256) {
        int s = src[e0 + i], d = dst[e0 + i];
        int slotD = atomicAdd(&curD[d >> 6], 1);
        edata[slotD] = (unsigned)s | ((unsigned)(d & 63) << 16);
        int slotS = atomicAdd(&curS[s >> 6], 1);
        srcv[slotS] = (unsigned char)(s & 63);
    }
}

// ---------------------------------------------------------------------------
// P4 fused: src-side count -> norm_src; dst-side count+scatter -> offsets,
// norm_dst, sorted_src (ushort: node ids < 65536). One block per bucket.
__global__ __launch_bounds__(256) void p4_fused(
    const int* __restrict__ srcb_base, const unsigned char* __restrict__ srcv,
    const int* __restrict__ bucket_base, const unsigned int* __restrict__ edata,
    int* __restrict__ offsets, float* __restrict__ norm_src,
    float* __restrict__ norm_dst, unsigned short* __restrict__ sorted_src) {
    __shared__ int cntS[64], cntD[64], cur[64];
    int t = threadIdx.x, b = blockIdx.x;
    if (t < 64) { cntS[t] = 0; cntD[t] = 0; }
    __syncthreads();
    int s0 = srcb_base[b], s1 = srcb_base[b + 1];
    for (int i = s0 + t; i < s1; i += 256) atomicAdd(&cntS[srcv[i]], 1);
    int d0 = bucket_base[b], d1 = bucket_base[b + 1];
    for (int i = d0 + t; i < d1; i += 256)
        atomicAdd(&cntD[(edata[i] >> 16) & 63], 1);
    __syncthreads();
    if (t == 0) {
        int run = 0;
        for (int i = 0; i < 64; i++) { cur[i] = run; run += cntD[i]; }
    }
    __syncthreads();
    if (t < 64) {
        int node = b * 64 + t;
        if (node < N_NODES) {
            norm_src[node] = rsqrtf(fmaxf((float)cntS[t], 1.0f));
            offsets[node] = d0 + cur[t];
            norm_dst[node] = rsqrtf(fmaxf((float)cntD[t], 1.0f));
        }
    }
    __syncthreads();
    for (int i = d0 + t; i < d1; i += 256) {
        unsigned e = edata[i];
        int slot = atomicAdd(&cur[(e >> 16) & 63], 1);
        sorted_src[d0 + slot] = (unsigned short)(e & 0xFFFFu);
    }
}

// ---------------------------------------------------------------------------
// agg1 + FUSED gemm2 (r8): one wave per dst node. Gather/accumulate as
// before; after the xor-16/32 butterfly ALL 64 lanes hold the full edge-sum
// for their col-group (lane&15)*8. Epilogue: h1 = relu(acc*nd+b1)*ns in f32
// (no bf16 quantization), then per-lane partial dot against W2tf[40][128]
// (quad q owns cols q*10..+10), 4-level shfl-xor reduce over the 16 m-lanes,
// pack hi|lo bf16 into H2u (dense stride 40). Deletes the 51MB H1
// round-trip and the gemm2 kernel entirely.
#define FMA8(W, NS)                                                   \
    acc0 = fmaf(__uint_as_float((W).x << 16), NS, acc0);              \
    acc1 = fmaf(__uint_as_float((W).x & 0xffff0000u), NS, acc1);      \
    acc2 = fmaf(__uint_as_float((W).y << 16), NS, acc2);              \
    acc3 = fmaf(__uint_as_float((W).y & 0xffff0000u), NS, acc3);      \
    acc4 = fmaf(__uint_as_float((W).z << 16), NS, acc4);              \
    acc5 = fmaf(__uint_as_float((W).z & 0xffff0000u), NS, acc5);      \
    acc6 = fmaf(__uint_as_float((W).w << 16), NS, acc6);              \
    acc7 = fmaf(__uint_as_float((W).w & 0xffff0000u), NS, acc7);

__global__ __launch_bounds__(256) void agg1_kernel(
    const int* __restrict__ offsets, const unsigned short* __restrict__ sorted_src,
    const unsigned short* __restrict__ Hb, const float* __restrict__ norm_dst,
    const float* __restrict__ norm_src, const float* __restrict__ b1,
    const float* __restrict__ W2tf, unsigned int* __restrict__ H2u) {
    int wid = (blockIdx.x * 256 + threadIdx.x) >> 6;
    int lane = threadIdx.x & 63;
    if (wid >= N_NODES) return;
    int start = offsets[wid], end = offsets[wid + 1];
    int quad = lane >> 4;
    int m = lane & 15;
    int c8 = m * 8;
    float acc0 = 0.f, acc1 = 0.f, acc2 = 0.f, acc3 = 0.f;
    float acc4 = 0.f, acc5 = 0.f, acc6 = 0.f, acc7 = 0.f;
    int base = start;
    for (; base + 16 <= end; base += 16) {
        int e0 = sorted_src[base + quad];
        int e1 = sorted_src[base + 4 + quad];
        int e2 = sorted_src[base + 8 + quad];
        int e3 = sorted_src[base + 12 + quad];
        float n0 = norm_src[e0], n1 = norm_src[e1];
        float n2 = norm_src[e2], n3 = norm_src[e3];
        uint4 w0 = *(const uint4*)&Hb[(size_t)e0 * N_HIDDEN + c8];
        uint4 w1 = *(const uint4*)&Hb[(size_t)e1 * N_HIDDEN + c8];
        uint4 w2 = *(const uint4*)&Hb[(size_t)e2 * N_HIDDEN + c8];
        uint4 w3 = *(const uint4*)&Hb[(size_t)e3 * N_HIDDEN + c8];
        FMA8(w0, n0);
        FMA8(w1, n1);
        FMA8(w2, n2);
        FMA8(w3, n3);
    }
    for (; base + 4 <= end; base += 4) {
        int e = sorted_src[base + quad];
        float n = norm_src[e];
        uint4 w = *(const uint4*)&Hb[(size_t)e * N_HIDDEN + c8];
        FMA8(w, n);
    }
    int rem = end - base;
    if (quad < rem) {
        int e = sorted_src[base + quad];
        float n = norm_src[e];
        uint4 w = *(const uint4*)&Hb[(size_t)e * N_HIDDEN + c8];
        FMA8(w, n);
    }
    acc0 += __shfl_xor(acc0, 16); acc0 += __shfl_xor(acc0, 32);
    acc1 += __shfl_xor(acc1, 16); acc1 += __shfl_xor(acc1, 32);
    acc2 += __shfl_xor(acc2, 16); acc2 += __shfl_xor(acc2, 32);
    acc3 += __shfl_xor(acc3, 16); acc3 += __shfl_xor(acc3, 32);
    acc4 += __shfl_xor(acc4, 16); acc4 += __shfl_xor(acc4, 32);
    acc5 += __shfl_xor(acc5, 16); acc5 += __shfl_xor(acc5, 32);
    acc6 += __shfl_xor(acc6, 16); acc6 += __shfl_xor(acc6, 32);
    acc7 += __shfl_xor(acc7, 16); acc7 += __shfl_xor(acc7, 32);

    // ---- fused gemm2 epilogue ----
    float nd = norm_dst[wid];
    float ns = norm_src[wid];
    float4 ba = *(const float4*)&b1[c8];
    float4 bb = *(const float4*)&b1[c8 + 4];
    float h0 = fmaxf(acc0 * nd + ba.x, 0.f) * ns;
    float h1 = fmaxf(acc1 * nd + ba.y, 0.f) * ns;
    float h2 = fmaxf(acc2 * nd + ba.z, 0.f) * ns;
    float h3 = fmaxf(acc3 * nd + ba.w, 0.f) * ns;
    float h4 = fmaxf(acc4 * nd + bb.x, 0.f) * ns;
    float h5 = fmaxf(acc5 * nd + bb.y, 0.f) * ns;
    float h6 = fmaxf(acc6 * nd + bb.z, 0.f) * ns;
    float h7 = fmaxf(acc7 * nd + bb.w, 0.f) * ns;

    // quad q computes cols q*10..q*10+9; lane (m) contributes k=8m..8m+8
    float pc[10];
#pragma unroll
    for (int c = 0; c < 10; c++) {
        const float* wr = W2tf + (quad * 10 + c) * 128 + c8;
        float4 wa = *(const float4*)wr;
        float4 wb2 = *(const float4*)(wr + 4);
        float s = fmaf(h0, wa.x, 0.f);
        s = fmaf(h1, wa.y, s);
        s = fmaf(h2, wa.z, s);
        s = fmaf(h3, wa.w, s);
        s = fmaf(h4, wb2.x, s);
        s = fmaf(h5, wb2.y, s);
        s = fmaf(h6, wb2.z, s);
        s = fmaf(h7, wb2.w, s);
        pc[c] = s;
    }
#pragma unroll
    for (int off = 1; off < 16; off <<= 1) {
#pragma unroll
        for (int c = 0; c < 10; c++) pc[c] += __shfl_xor(pc[c], off);
    }
    if (m == 0) {
#pragma unroll
        for (int c = 0; c < 10; c++) {
            float v = pc[c];
            unsigned short hh = f2bf(v);
            unsigned short ll = f2bf(v - bf2f(hh));
            H2u[(size_t)wid * 40 + quad * 10 + c] = ((unsigned)hh << 16) | (unsigned)ll;
        }
    }
}

// ---------------------------------------------------------------------------
// agg2: one wave per dst node; 16 edges in flight (4 uint4/lane), packed
// hi|lo bf16 reconstruction, butterfly reduce. H2u dense stride 40.
#define ACC4(V)                                                               \
    acc.x += __uint_as_float((V).x & 0xffff0000u) + __uint_as_float((V).x << 16); \
    acc.y += __uint_as_float((V).y & 0xffff0000u) + __uint_as_float((V).y << 16); \
    acc.z += __uint_as_float((V).z & 0xffff0000u) + __uint_as_float((V).z << 16); \
    acc.w += __uint_as_float((V).w & 0xffff0000u) + __uint_as_float((V).w << 16);

__global__ __launch_bounds__(256) void agg2_kernel(
    const int* __restrict__ offsets, const unsigned short* __restrict__ sorted_src,
    const unsigned int* __restrict__ H2u, const float* __restrict__ norm_dst,
    const float* __restrict__ b2, float* __restrict__ OUT) {
    int wid = (blockIdx.x * 256 + threadIdx.x) >> 6;
    int lane = threadIdx.x & 63;
    if (wid >= N_NODES) return;
    int start = offsets[wid], end = offsets[wid + 1];
    int quad = lane >> 4;
    int c4 = (lane & 15) * 4;
    bool active = c4 < N_CLASSES;
    float4 acc = make_float4(0.f, 0.f, 0.f, 0.f);
    int base = start;
    for (; base + 16 <= end; base += 16) {
        int e0 = sorted_src[base + quad];
        int e1 = sorted_src[base + 4 + quad];
        int e2 = sorted_src[base + 8 + quad];
        int e3 = sorted_src[base + 12 + quad];
        if (active) {
            uint4 v0 = *(const uint4*)&H2u[(size_t)e0 * 40 + c4];
            uint4 v1 = *(const uint4*)&H2u[(size_t)e1 * 40 + c4];
            uint4 v2 = *(const uint4*)&H2u[(size_t)e2 * 40 + c4];
            uint4 v3 = *(const uint4*)&H2u[(size_t)e3 * 40 + c4];
            ACC4(v0); ACC4(v1); ACC4(v2); ACC4(v3);
        }
    }
    for (; base + 4 <= end; base += 4) {
        int e = sorted_src[base + quad];
        if (active) {
            uint4 v = *(const uint4*)&H2u[(size_t)e * 40 + c4];
            ACC4(v);
        }
    }
    int rem = end - base;
    if (quad < rem && active) {
        int e = sorted_src[base + quad];
        uint4 v = *(const uint4*)&H2u[(size_t)e * 40 + c4];
        ACC4(v);
    }
    acc.x += __shfl_xor(acc.x, 16); acc.x += __shfl_xor(acc.x, 32);
    acc.y += __shfl_xor(acc.y, 16); acc.y += __shfl_xor(acc.y, 32);
    acc.z += __shfl_xor(acc.z, 16); acc.z += __shfl_xor(acc.z, 32);
    acc.w += __shfl_xor(acc.w, 16); acc.w += __shfl_xor(acc.w, 32);
    if (lane < 10) {
        float nd = norm_dst[wid];
        float4 b = *(const float4*)&b2[lane * 4];
        acc.x = acc.x * nd + b.x;
        acc.y = acc.y * nd + b.y;
        acc.z = acc.z * nd + b.z;
        acc.w = acc.w * nd + b.w;
        *(float4*)&OUT[(size_t)wid * N_CLASSES + lane * 4] = acc;
    }
}

// ---------------------------------------------------------------------------
extern "C" void kernel_launch(void* const* d_in, const int* in_sizes, int n_in,
                              void* d_out, int out_size, void* d_ws, size_t ws_size,
                              hipStream_t stream) {
    const float* X   = (const float*)d_in[0];
    const float* W1  = (const float*)d_in[1];
    const float* b1  = (const float*)d_in[2];
    const float* W2  = (const float*)d_in[3];
    const float* b2  = (const float*)d_in[4];
    const int*   src = (const int*)d_in[5];
    const int*   dst = (const int*)d_in[6];
    float* out = (float*)d_out;

    // workspace layout (4B units). regionA time-shared:
    //   phase 1: histD|histS|baseD|baseS|totD|totS      [dead after p3]
    //   phase 3: H2u packed u32 50000x40 (2M dwords)    [written at agg1]
    // Hb has its own region (written by megaA while phase-1 data live).
    float* norm_src   = (float*)d_ws;                     // 50000
    float* norm_dst   = norm_src + N_NODES;               // 50000
    int*   offsets    = (int*)(norm_dst + N_NODES);       // 50016 (incl pad)
    int*   bucket_base = offsets + N_NODES + 16;          // 800
    int*   srcb_base  = bucket_base + 800;                // 800
    unsigned int* edata = (unsigned int*)(srcb_base + 800);       // 1.6M
    unsigned char* srcv = (unsigned char*)(edata + N_EDGES);      // 400K dwords
    unsigned short* sorted_src =
        (unsigned short*)((int*)(edata + N_EDGES) + 400000);      // 1.6M ushort
    int*   regionA    = (int*)(edata + N_EDGES) + 400000 + 800000; // 3.2M dwords
    int*   histD      = regionA;
    int*   histS      = regionA + 625600;
    int*   baseD      = regionA + 1251200;
    int*   baseS      = regionA + 1876800;
    int*   totD       = regionA + 2502400;                // 800
    int*   totS       = regionA + 2503200;                // 800
    unsigned int* H2u = (unsigned int*)regionA;           // phase 3 (2M)
    unsigned short* W1ch = (unsigned short*)(regionA + 3200000);  // 512*128
    unsigned short* W1cl = W1ch + IN_FEATS * N_HIDDEN;
    float* W2tf          = (float*)(W1cl + IN_FEATS * N_HIDDEN);  // 40*128 f32
    unsigned short* Hb   = (unsigned short*)(W2tf + N_CLASSES * N_HIDDEN);
                                                          // 50000x128 bf16

    // setup grid: W1 (65536) + W2tf (5120) = 70656 = 276 * 256 exactly
    setup_cvt<<<(IN_FEATS * N_HIDDEN + N_CLASSES * N_HIDDEN) / 256, 256, 0, stream>>>(
        W1, W2, W1ch, W1cl, W2tf);
    megaA<<<NBLK + NBKT, 256, 0, stream>>>(src, dst, histD, histS, X, W1ch, W1cl, Hb);
    p2_local<<<(NBKT + 3) / 4, 256, 0, stream>>>(histD, histS, baseD, baseS, totD, totS);
    p2_small<<<1, 1024, 0, stream>>>(totD, totS, bucket_base, srcb_base, offsets);
    p3_scatter<<<NBLK, 256, 0, stream>>>(src, dst, baseD, baseS, bucket_base, srcb_base,
                                         edata, srcv);
    p4_fused<<<NBKT, 256, 0, stream>>>(srcb_base, srcv, bucket_base, edata,
                                       offsets, norm_src, norm_dst, sorted_src);
    agg1_kernel<<<(N_NODES + 3) / 4, 256, 0, stream>>>(offsets, sorted_src, Hb, norm_dst,
                                                       norm_src, b1, W2tf, H2u);
    agg2_kernel<<<(N_NODES + 3) / 4, 256, 0, stream>>>(offsets, sorted_src, H2u, norm_dst, b2, out);
}

// Round 9
// 374.631 us; speedup vs baseline: 1.0273x; 1.0273x over previous
//
#include <hip/hip_runtime.h>
#include <hip/hip_bf16.h>

#define N_NODES 50000
#define N_EDGES 1600000
#define IN_FEATS 512
#define N_HIDDEN 128
#define N_CLASSES 40
#define NBKT 782      // ceil(50000/64) buckets of 64 nodes
#define NBLK 800      // partition blocks
#define EPB 2000      // edges per partition block (800*2000 = 1.6M exact)

typedef __attribute__((ext_vector_type(8))) short bf16x8;
typedef __attribute__((ext_vector_type(4))) float f32x4;

__device__ __forceinline__ unsigned short f2bf(float f) {
    unsigned u = __float_as_uint(f);
    u = (u + 0x7FFFu + ((u >> 16) & 1u)) >> 16;   // round-to-nearest-even
    return (unsigned short)u;
}
__device__ __forceinline__ float bf2f(unsigned short h) {
    return __uint_as_float(((unsigned)h) << 16);
}
// packed f32x2 -> bf16x2 (RTNE), lowers to v_cvt_pk_bf16_f32 on gfx950
__device__ __forceinline__ unsigned pk_bf(float a, float b) {
    __hip_bfloat162 h = __float22bfloat162_rn(make_float2(a, b));
    union { __hip_bfloat162 v; unsigned u; } c;
    c.v = h;
    return c.u;   // low 16 = bf(a), high 16 = bf(b)
}

// 8 floats (two float4) -> hi/lo bf16x8 fragments, in registers.
__device__ __forceinline__ void cvt8(float4 a, float4 b, bf16x8& h, bf16x8& l) {
    unsigned h0 = pk_bf(a.x, a.y), h1 = pk_bf(a.z, a.w);
    unsigned h2 = pk_bf(b.x, b.y), h3 = pk_bf(b.z, b.w);
    unsigned l0 = pk_bf(a.x - __uint_as_float(h0 << 16),
                        a.y - __uint_as_float(h0 & 0xffff0000u));
    unsigned l1 = pk_bf(a.z - __uint_as_float(h1 << 16),
                        a.w - __uint_as_float(h1 & 0xffff0000u));
    unsigned l2 = pk_bf(b.x - __uint_as_float(h2 << 16),
                        b.y - __uint_as_float(h2 & 0xffff0000u));
    unsigned l3 = pk_bf(b.z - __uint_as_float(h3 << 16),
                        b.w - __uint_as_float(h3 & 0xffff0000u));
    union U { unsigned u[4]; bf16x8 v; };
    U H; H.u[0] = h0; H.u[1] = h1; H.u[2] = h2; H.u[3] = h3; h = H.v;
    U L; L.u[0] = l0; L.u[1] = l1; L.u[2] = l2; L.u[3] = l3; l = L.v;
}

__device__ __forceinline__ int imin(int a, int b) { return a < b ? a : b; }

// ---------------------------------------------------------------------------
// setup: W1 -> k-chunked bf16 hi/lo [kc][col][ki]; W2 -> f32 transposed
// [40][128] (consumed by agg1's fused gemm2 epilogue).
__global__ __launch_bounds__(256) void setup_cvt(
    const float* __restrict__ W1, const float* __restrict__ W2,
    unsigned short* __restrict__ W1ch, unsigned short* __restrict__ W1cl,
    float* __restrict__ W2tf) {
    int i = blockIdx.x * 256 + threadIdx.x;
    if (i < IN_FEATS * N_HIDDEN) {
        int k = i >> 7, c = i & 127;
        float v = W1[i];
        unsigned short h = f2bf(v);
        int o = (k >> 5) * 4096 + c * 32 + (k & 31);
        W1ch[o] = h;
        W1cl[o] = f2bf(v - bf2f(h));
    } else {
        int j = i - IN_FEATS * N_HIDDEN;    // 0..5119 (grid sized exactly)
        int c = j >> 7, k = j & 127;
        W2tf[j] = W2[k * N_CLASSES + c];
    }
}

// ---------------------------------------------------------------------------
// megaA: blocks [0,NBKT) = gemm1 tiles; blocks [NBKT,NBKT+NBLK) = p1_hist.
// gemm1 r7 structure (60us plateau, closed): lane-linear LDS, two chunks per
// barrier, 4 LDS buffers.

#define MFJ(AH, AL, BH, BL, ACC)                                              \
    ACC = __builtin_amdgcn_mfma_f32_16x16x32_bf16(AH, BH, ACC, 0, 0, 0);      \
    ACC = __builtin_amdgcn_mfma_f32_16x16x32_bf16(AH, BL, ACC, 0, 0, 0);      \
    ACC = __builtin_amdgcn_mfma_f32_16x16x32_bf16(AL, BH, ACC, 0, 0, 0);

#define CHUNK_COMPUTE(FRAGBASE, KC)                                           \
    {                                                                         \
        const unsigned short* wk  = wbh + (KC) * 4096;                        \
        const unsigned short* wkl = wbl + (KC) * 4096;                        \
        bf16x8 bh0 = *(const bf16x8*)(wk);                                    \
        bf16x8 bh1 = *(const bf16x8*)(wk + 512);                              \
        bf16x8 bl0 = *(const bf16x8*)(wkl);                                   \
        bf16x8 bl1 = *(const bf16x8*)(wkl + 512);                             \
        const unsigned short* fb = (FRAGBASE);                                \
        bf16x8 ah0 = *(const bf16x8*)(fb + (0 * 64 + lane) * 8);              \
        bf16x8 ah1 = *(const bf16x8*)(fb + (1 * 64 + lane) * 8);              \
        bf16x8 ah2 = *(const bf16x8*)(fb + (2 * 64 + lane) * 8);              \
        bf16x8 ah3 = *(const bf16x8*)(fb + (3 * 64 + lane) * 8);              \
        bf16x8 al0 = *(const bf16x8*)(fb + 2048 + (0 * 64 + lane) * 8);       \
        bf16x8 al1 = *(const bf16x8*)(fb + 2048 + (1 * 64 + lane) * 8);       \
        bf16x8 al2 = *(const bf16x8*)(fb + 2048 + (2 * 64 + lane) * 8);       \
        bf16x8 al3 = *(const bf16x8*)(fb + 2048 + (3 * 64 + lane) * 8);       \
        MFJ(ah0, al0, bh0, bl0, acc[0][0]) MFJ(ah0, al0, bh1, bl1, acc[0][1]) \
        MFJ(ah1, al1, bh0, bl0, acc[1][0]) MFJ(ah1, al1, bh1, bl1, acc[1][1]) \
        MFJ(ah2, al2, bh0, bl0, acc[2][0]) MFJ(ah2, al2, bh1, bl1, acc[2][1]) \
        MFJ(ah3, al3, bh0, bl0, acc[3][0]) MFJ(ah3, al3, bh1, bl1, acc[3][1]) \
    }

__global__ __launch_bounds__(256) void megaA(
    const int* __restrict__ src, const int* __restrict__ dst,
    int* __restrict__ histD, int* __restrict__ histS,
    const float* __restrict__ X, const unsigned short* __restrict__ Wch,
    const unsigned short* __restrict__ Wcl, unsigned short* __restrict__ Hb) {
    __shared__ __align__(16) unsigned char smem[32768];
    const int tid = threadIdx.x;

    if (blockIdx.x >= NBKT) {
        // ---- p1_hist ----
        int* hd = (int*)smem;
        int* hs = hd + NBKT;
        int b = blockIdx.x - NBKT;
        for (int i = tid; i < NBKT; i += 256) { hd[i] = 0; hs[i] = 0; }
        __syncthreads();
        int e0 = b * EPB;
        for (int i = tid; i < EPB; i += 256) {
            atomicAdd(&hd[dst[e0 + i] >> 6], 1);
            atomicAdd(&hs[src[e0 + i] >> 6], 1);
        }
        __syncthreads();
        for (int i = tid; i < NBKT; i += 256) {
            histD[b * NBKT + i] = hd[i];
            histS[b * NBKT + i] = hs[i];
        }
        return;
    }
    // ---- gemm1: 64 rows, split-precision bf16 MFMA, unscaled output ----
    typedef unsigned short ush;
    ush* lds = (ush*)smem;   // set s at + s*8192 ush; within set:
                             // chunkA hi +0, lo +2048; chunkB hi +4096, lo +6144

    const int lane = tid & 63;
    const int wv = tid >> 6;
    const int m = lane & 15;
    const int q = lane >> 4;
    const int q8 = q * 8;
    const int row0 = blockIdx.x * 64;

    const unsigned short* wbh = Wch + (wv * 32 + m) * 32 + q8;
    const unsigned short* wbl = Wcl + (wv * 32 + m) * 32 + q8;

    const int srow = (tid >> 6) * 16 + (tid & 15);      // row within tile
    const int sq8  = ((tid >> 4) & 3) * 8;              // col group * 8
    const float* xp = &X[(size_t)imin(row0 + srow, N_NODES - 1) * IN_FEATS + sq8];

    f32x4 acc[4][2];
#pragma unroll
    for (int i = 0; i < 4; i++)
#pragma unroll
        for (int j = 0; j < 2; j++) acc[i][j] = (f32x4){0.f, 0.f, 0.f, 0.f};

    // prologue: stage pair 0 (chunks 0,1) into set 0; pair 1 X into regs
    {
        float4 c00 = *(const float4*)(xp),      c01 = *(const float4*)(xp + 4);
        float4 c10 = *(const float4*)(xp + 32), c11 = *(const float4*)(xp + 36);
        bf16x8 h, l;
        cvt8(c00, c01, h, l);
        *(bf16x8*)(lds + tid * 8) = h;
        *(bf16x8*)(lds + 2048 + tid * 8) = l;
        cvt8(c10, c11, h, l);
        *(bf16x8*)(lds + 4096 + tid * 8) = h;
        *(bf16x8*)(lds + 6144 + tid * 8) = l;
    }
    float4 a00 = *(const float4*)(xp + 64), a01 = *(const float4*)(xp + 68);
    float4 a10 = *(const float4*)(xp + 96), a11 = *(const float4*)(xp + 100);
    __syncthreads();

    for (int pp = 0; pp < 8; pp++) {
        if (pp < 7) {
            ush* bs = lds + ((pp + 1) & 1) * 8192;
            bf16x8 h, l;
            cvt8(a00, a01, h, l);
            *(bf16x8*)(bs + tid * 8) = h;
            *(bf16x8*)(bs + 2048 + tid * 8) = l;
            cvt8(a10, a11, h, l);
            *(bf16x8*)(bs + 4096 + tid * 8) = h;
            *(bf16x8*)(bs + 6144 + tid * 8) = l;
        }
        if (pp < 6) {
            const float* xq = xp + (pp + 2) * 64;
            a00 = *(const float4*)(xq);      a01 = *(const float4*)(xq + 4);
            a10 = *(const float4*)(xq + 32); a11 = *(const float4*)(xq + 36);
        }
        const ush* br = lds + (pp & 1) * 8192;
        CHUNK_COMPUTE(br,        2 * pp)
        CHUNK_COMPUTE(br + 4096, 2 * pp + 1)
        if (pp < 7) __syncthreads();
    }

#pragma unroll
    for (int i = 0; i < 4; i++) {
#pragma unroll
        for (int r = 0; r < 4; r++) {
            int grow = row0 + i * 16 + q * 4 + r;
            if (grow < N_NODES) {
#pragma unroll
                for (int j = 0; j < 2; j++)
                    Hb[(size_t)grow * N_HIDDEN + wv * 32 + j * 16 + m] = f2bf(acc[i][j][r]);
            }
        }
    }
}

// ---------------------------------------------------------------------------
// P2a: one wave per bucket — parallel scan over the 800-block dimension.
__global__ __launch_bounds__(256) void p2_local(
    const int* __restrict__ histD, const int* __restrict__ histS,
    int* __restrict__ baseD, int* __restrict__ baseS,
    int* __restrict__ totD, int* __restrict__ totS) {
    int wv = threadIdx.x >> 6, lane = threadIdx.x & 63;
    int w = blockIdx.x * 4 + wv;
    if (w >= NBKT) return;
    int runD = 0, runS = 0;
#pragma unroll
    for (int c = 0; c < 13; c++) {
        int blk = c * 64 + lane;
        int vD = 0, vS = 0;
        if (blk < NBLK) {
            vD = histD[blk * NBKT + w];
            vS = histS[blk * NBKT + w];
        }
        int iD = vD, iS = vS;
#pragma unroll
        for (int off = 1; off < 64; off <<= 1) {
            int tD = __shfl_up(iD, off);
            int tS = __shfl_up(iS, off);
            if (lane >= off) { iD += tD; iS += tS; }
        }
        if (blk < NBLK) {
            baseD[blk * NBKT + w] = runD + iD - vD;
            baseS[blk * NBKT + w] = runS + iS - vS;
        }
        runD += __shfl(iD, 63);
        runS += __shfl(iS, 63);
    }
    if (lane == 0) { totD[w] = runD; totS[w] = runS; }
}

// P2b: single-block scan over the 782 bucket totals only.
__global__ __launch_bounds__(1024) void p2_small(
    const int* __restrict__ totD, const int* __restrict__ totS,
    int* __restrict__ bucket_base, int* __restrict__ srcb_base,
    int* __restrict__ offsets) {
    __shared__ int part[1024];
    int t = threadIdx.x;
    int v = (t < NBKT) ? totD[t] : 0;
    part[t] = v;
    __syncthreads();
    for (int off = 1; off < 1024; off <<= 1) {
        int x = (t >= off) ? part[t - off] : 0;
        __syncthreads();
        part[t] += x;
        __syncthreads();
    }
    if (t < NBKT) bucket_base[t] = part[t] - v;
    if (t == 0) { bucket_base[NBKT] = N_EDGES; offsets[N_NODES] = N_EDGES; }
    __syncthreads();
    v = (t < NBKT) ? totS[t] : 0;
    part[t] = v;
    __syncthreads();
    for (int off = 1; off < 1024; off <<= 1) {
        int x = (t >= off) ? part[t - off] : 0;
        __syncthreads();
        part[t] += x;
        __syncthreads();
    }
    if (t < NBKT) srcb_base[t] = part[t] - v;
    if (t == 0) srcb_base[NBKT] = N_EDGES;
}

// ---------------------------------------------------------------------------
// P3: scatter edges into bucket-partitioned arrays via LDS cursors.
__global__ __launch_bounds__(256) void p3_scatter(
    const int* __restrict__ src, const int* __restrict__ dst,
    const int* __restrict__ baseD, const int* __restrict__ baseS,
    const int* __restrict__ bucket_base, const int* __restrict__ srcb_base,
    unsigned int* __restrict__ edata, unsigned char* __restrict__ srcv) {
    __shared__ int curD[NBKT], curS[NBKT];
    int t = threadIdx.x, b = blockIdx.x;
    for (int i = t; i < NBKT; i += 256) {
        curD[i] = bucket_base[i] + baseD[b * NBKT + i];
        curS[i] = srcb_base[i] + baseS[b * NBKT + i];
    }
    __syncthreads();
    int e0 = b * EPB;
    for (int i = t; i < EPB; i += 256) {
        int s = src[e0 + i], d = dst[e0 + i];
        int slotD = atomicAdd(&curD[d >> 6], 1);
        edata[slotD] = (unsigned)s | ((unsigned)(d & 63) << 16);
        int slotS = atomicAdd(&curS[s >> 6], 1);
        srcv[slotS] = (unsigned char)(s & 63);
    }
}

// ---------------------------------------------------------------------------
// P4 fused: src-side count -> norm_src; dst-side count+scatter -> offsets,
// norm_dst, sorted_src (ushort: node ids < 65536). One block per bucket.
__global__ __launch_bounds__(256) void p4_fused(
    const int* __restrict__ srcb_base, const unsigned char* __restrict__ srcv,
    const int* __restrict__ bucket_base, const unsigned int* __restrict__ edata,
    int* __restrict__ offsets, float* __restrict__ norm_src,
    float* __restrict__ norm_dst, unsigned short* __restrict__ sorted_src) {
    __shared__ int cntS[64], cntD[64], cur[64];
    int t = threadIdx.x, b = blockIdx.x;
    if (t < 64) { cntS[t] = 0; cntD[t] = 0; }
    __syncthreads();
    int s0 = srcb_base[b], s1 = srcb_base[b + 1];
    for (int i = s0 + t; i < s1; i += 256) atomicAdd(&cntS[srcv[i]], 1);
    int d0 = bucket_base[b], d1 = bucket_base[b + 1];
    for (int i = d0 + t; i < d1; i += 256)
        atomicAdd(&cntD[(edata[i] >> 16) & 63], 1);
    __syncthreads();
    if (t == 0) {
        int run = 0;
        for (int i = 0; i < 64; i++) { cur[i] = run; run += cntD[i]; }
    }
    __syncthreads();
    if (t < 64) {
        int node = b * 64 + t;
        if (node < N_NODES) {
            norm_src[node] = rsqrtf(fmaxf((float)cntS[t], 1.0f));
            offsets[node] = d0 + cur[t];
            norm_dst[node] = rsqrtf(fmaxf((float)cntD[t], 1.0f));
        }
    }
    __syncthreads();
    for (int i = d0 + t; i < d1; i += 256) {
        unsigned e = edata[i];
        int slot = atomicAdd(&cur[(e >> 16) & 63], 1);
        sorted_src[d0 + slot] = (unsigned short)(e & 0xFFFFu);
    }
}

// ---------------------------------------------------------------------------
// agg1 + fused gemm2, r9: W2 fragment HOISTED INTO REGISTERS (once per wave;
// 80 VGPR, statically indexed) and GRID-STRIDE waves over nodes (~8 nodes
// per wave) so the W2/b1 load amortizes. r8's bug: every wave re-read the
// whole 20KB W2tf per node = 1GB of L1/L2 traffic (+35us). Epilogue is now
// pure VALU: 80 fma + 40 shfl per node.
#define FMA8(W, NS)                                                   \
    acc0 = fmaf(__uint_as_float((W).x << 16), NS, acc0);              \
    acc1 = fmaf(__uint_as_float((W).x & 0xffff0000u), NS, acc1);      \
    acc2 = fmaf(__uint_as_float((W).y << 16), NS, acc2);              \
    acc3 = fmaf(__uint_as_float((W).y & 0xffff0000u), NS, acc3);      \
    acc4 = fmaf(__uint_as_float((W).z << 16), NS, acc4);              \
    acc5 = fmaf(__uint_as_float((W).z & 0xffff0000u), NS, acc5);      \
    acc6 = fmaf(__uint_as_float((W).w << 16), NS, acc6);              \
    acc7 = fmaf(__uint_as_float((W).w & 0xffff0000u), NS, acc7);

#define AGG1_BLOCKS 1536

__global__ __launch_bounds__(256) void agg1_kernel(
    const int* __restrict__ offsets, const unsigned short* __restrict__ sorted_src,
    const unsigned short* __restrict__ Hb, const float* __restrict__ norm_dst,
    const float* __restrict__ norm_src, const float* __restrict__ b1,
    const float* __restrict__ W2tf, unsigned int* __restrict__ H2u) {
    const int lane = threadIdx.x & 63;
    const int quad = lane >> 4;
    const int m = lane & 15;
    const int c8 = m * 8;

    // once-per-wave: W2 fragment (quad q, k-range c8..c8+8 of cols q*10..+10)
    float4 w2a[10], w2b[10];
#pragma unroll
    for (int c = 0; c < 10; c++) {
        const float* wr = W2tf + (quad * 10 + c) * 128 + c8;
        w2a[c] = *(const float4*)wr;
        w2b[c] = *(const float4*)(wr + 4);
    }
    const float4 ba = *(const float4*)&b1[c8];
    const float4 bb = *(const float4*)&b1[c8 + 4];

    const int nwaves = AGG1_BLOCKS * 4;
    const int wid0 = (blockIdx.x * 256 + threadIdx.x) >> 6;

    for (int wid = wid0; wid < N_NODES; wid += nwaves) {
        int start = offsets[wid], end = offsets[wid + 1];
        float acc0 = 0.f, acc1 = 0.f, acc2 = 0.f, acc3 = 0.f;
        float acc4 = 0.f, acc5 = 0.f, acc6 = 0.f, acc7 = 0.f;
        int base = start;
        for (; base + 16 <= end; base += 16) {
            int e0 = sorted_src[base + quad];
            int e1 = sorted_src[base + 4 + quad];
            int e2 = sorted_src[base + 8 + quad];
            int e3 = sorted_src[base + 12 + quad];
            float n0 = norm_src[e0], n1 = norm_src[e1];
            float n2 = norm_src[e2], n3 = norm_src[e3];
            uint4 w0 = *(const uint4*)&Hb[(size_t)e0 * N_HIDDEN + c8];
            uint4 w1 = *(const uint4*)&Hb[(size_t)e1 * N_HIDDEN + c8];
            uint4 w2 = *(const uint4*)&Hb[(size_t)e2 * N_HIDDEN + c8];
            uint4 w3 = *(const uint4*)&Hb[(size_t)e3 * N_HIDDEN + c8];
            FMA8(w0, n0);
            FMA8(w1, n1);
            FMA8(w2, n2);
            FMA8(w3, n3);
        }
        for (; base + 4 <= end; base += 4) {
            int e = sorted_src[base + quad];
            float n = norm_src[e];
            uint4 w = *(const uint4*)&Hb[(size_t)e * N_HIDDEN + c8];
            FMA8(w, n);
        }
        int rem = end - base;
        if (quad < rem) {
            int e = sorted_src[base + quad];
            float n = norm_src[e];
            uint4 w = *(const uint4*)&Hb[(size_t)e * N_HIDDEN + c8];
            FMA8(w, n);
        }
        acc0 += __shfl_xor(acc0, 16); acc0 += __shfl_xor(acc0, 32);
        acc1 += __shfl_xor(acc1, 16); acc1 += __shfl_xor(acc1, 32);
        acc2 += __shfl_xor(acc2, 16); acc2 += __shfl_xor(acc2, 32);
        acc3 += __shfl_xor(acc3, 16); acc3 += __shfl_xor(acc3, 32);
        acc4 += __shfl_xor(acc4, 16); acc4 += __shfl_xor(acc4, 32);
        acc5 += __shfl_xor(acc5, 16); acc5 += __shfl_xor(acc5, 32);
        acc6 += __shfl_xor(acc6, 16); acc6 += __shfl_xor(acc6, 32);
        acc7 += __shfl_xor(acc7, 16); acc7 += __shfl_xor(acc7, 32);

        // ---- fused gemm2 epilogue (register-resident W2) ----
        float nd = norm_dst[wid];
        float ns = norm_src[wid];
        float h0 = fmaxf(acc0 * nd + ba.x, 0.f) * ns;
        float h1 = fmaxf(acc1 * nd + ba.y, 0.f) * ns;
        float h2 = fmaxf(acc2 * nd + ba.z, 0.f) * ns;
        float h3 = fmaxf(acc3 * nd + ba.w, 0.f) * ns;
        float h4 = fmaxf(acc4 * nd + bb.x, 0.f) * ns;
        float h5 = fmaxf(acc5 * nd + bb.y, 0.f) * ns;
        float h6 = fmaxf(acc6 * nd + bb.z, 0.f) * ns;
        float h7 = fmaxf(acc7 * nd + bb.w, 0.f) * ns;

        float pc[10];
#pragma unroll
        for (int c = 0; c < 10; c++) {
            float s = fmaf(h0, w2a[c].x, 0.f);
            s = fmaf(h1, w2a[c].y, s);
            s = fmaf(h2, w2a[c].z, s);
            s = fmaf(h3, w2a[c].w, s);
            s = fmaf(h4, w2b[c].x, s);
            s = fmaf(h5, w2b[c].y, s);
            s = fmaf(h6, w2b[c].z, s);
            s = fmaf(h7, w2b[c].w, s);
            pc[c] = s;
        }
#pragma unroll
        for (int off = 1; off < 16; off <<= 1) {
#pragma unroll
            for (int c = 0; c < 10; c++) pc[c] += __shfl_xor(pc[c], off);
        }
        if (m == 0) {
#pragma unroll
            for (int c = 0; c < 10; c++) {
                float v = pc[c];
                unsigned short hh = f2bf(v);
                unsigned short ll = f2bf(v - bf2f(hh));
                H2u[(size_t)wid * 40 + quad * 10 + c] = ((unsigned)hh << 16) | (unsigned)ll;
            }
        }
    }
}

// ---------------------------------------------------------------------------
// agg2: one wave per dst node; 16 edges in flight (4 uint4/lane), packed
// hi|lo bf16 reconstruction, butterfly reduce. H2u dense stride 40.
#define ACC4(V)                                                               \
    acc.x += __uint_as_float((V).x & 0xffff0000u) + __uint_as_float((V).x << 16); \
    acc.y += __uint_as_float((V).y & 0xffff0000u) + __uint_as_float((V).y << 16); \
    acc.z += __uint_as_float((V).z & 0xffff0000u) + __uint_as_float((V).z << 16); \
    acc.w += __uint_as_float((V).w & 0xffff0000u) + __uint_as_float((V).w << 16);

__global__ __launch_bounds__(256) void agg2_kernel(
    const int* __restrict__ offsets, const unsigned short* __restrict__ sorted_src,
    const unsigned int* __restrict__ H2u, const float* __restrict__ norm_dst,
    const float* __restrict__ b2, float* __restrict__ OUT) {
    int wid = (blockIdx.x * 256 + threadIdx.x) >> 6;
    int lane = threadIdx.x & 63;
    if (wid >= N_NODES) return;
    int start = offsets[wid], end = offsets[wid + 1];
    int quad = lane >> 4;
    int c4 = (lane & 15) * 4;
    bool active = c4 < N_CLASSES;
    float4 acc = make_float4(0.f, 0.f, 0.f, 0.f);
    int base = start;
    for (; base + 16 <= end; base += 16) {
        int e0 = sorted_src[base + quad];
        int e1 = sorted_src[base + 4 + quad];
        int e2 = sorted_src[base + 8 + quad];
        int e3 = sorted_src[base + 12 + quad];
        if (active) {
            uint4 v0 = *(const uint4*)&H2u[(size_t)e0 * 40 + c4];
            uint4 v1 = *(const uint4*)&H2u[(size_t)e1 * 40 + c4];
            uint4 v2 = *(const uint4*)&H2u[(size_t)e2 * 40 + c4];
            uint4 v3 = *(const uint4*)&H2u[(size_t)e3 * 40 + c4];
            ACC4(v0); ACC4(v1); ACC4(v2); ACC4(v3);
        }
    }
    for (; base + 4 <= end; base += 4) {
        int e = sorted_src[base + quad];
        if (active) {
            uint4 v = *(const uint4*)&H2u[(size_t)e * 40 + c4];
            ACC4(v);
        }
    }
    int rem = end - base;
    if (quad < rem && active) {
        int e = sorted_src[base + quad];
        uint4 v = *(const uint4*)&H2u[(size_t)e * 40 + c4];
        ACC4(v);
    }
    acc.x += __shfl_xor(acc.x, 16); acc.x += __shfl_xor(acc.x, 32);
    acc.y += __shfl_xor(acc.y, 16); acc.y += __shfl_xor(acc.y, 32);
    acc.z += __shfl_xor(acc.z, 16); acc.z += __shfl_xor(acc.z, 32);
    acc.w += __shfl_xor(acc.w, 16); acc.w += __shfl_xor(acc.w, 32);
    if (lane < 10) {
        float nd = norm_dst[wid];
        float4 b = *(const float4*)&b2[lane * 4];
        acc.x = acc.x * nd + b.x;
        acc.y = acc.y * nd + b.y;
        acc.z = acc.z * nd + b.z;
        acc.w = acc.w * nd + b.w;
        *(float4*)&OUT[(size_t)wid * N_CLASSES + lane * 4] = acc;
    }
}

// ---------------------------------------------------------------------------
extern "C" void kernel_launch(void* const* d_in, const int* in_sizes, int n_in,
                              void* d_out, int out_size, void* d_ws, size_t ws_size,
                              hipStream_t stream) {
    const float* X   = (const float*)d_in[0];
    const float* W1  = (const float*)d_in[1];
    const float* b1  = (const float*)d_in[2];
    const float* W2  = (const float*)d_in[3];
    const float* b2  = (const float*)d_in[4];
    const int*   src = (const int*)d_in[5];
    const int*   dst = (const int*)d_in[6];
    float* out = (float*)d_out;

    // workspace layout (4B units). regionA time-shared:
    //   phase 1: histD|histS|baseD|baseS|totD|totS      [dead after p3]
    //   phase 3: H2u packed u32 50000x40 (2M dwords)    [written at agg1]
    // Hb has its own region (written by megaA while phase-1 data live).
    float* norm_src   = (float*)d_ws;                     // 50000
    float* norm_dst   = norm_src + N_NODES;               // 50000
    int*   offsets    = (int*)(norm_dst + N_NODES);       // 50016 (incl pad)
    int*   bucket_base = offsets + N_NODES + 16;          // 800
    int*   srcb_base  = bucket_base + 800;                // 800
    unsigned int* edata = (unsigned int*)(srcb_base + 800);       // 1.6M
    unsigned char* srcv = (unsigned char*)(edata + N_EDGES);      // 400K dwords
    unsigned short* sorted_src =
        (unsigned short*)((int*)(edata + N_EDGES) + 400000);      // 1.6M ushort
    int*   regionA    = (int*)(edata + N_EDGES) + 400000 + 800000; // 3.2M dwords
    int*   histD      = regionA;
    int*   histS      = regionA + 625600;
    int*   baseD      = regionA + 1251200;
    int*   baseS      = regionA + 1876800;
    int*   totD       = regionA + 2502400;                // 800
    int*   totS       = regionA + 2503200;                // 800
    unsigned int* H2u = (unsigned int*)regionA;           // phase 3 (2M)
    unsigned short* W1ch = (unsigned short*)(regionA + 3200000);  // 512*128
    unsigned short* W1cl = W1ch + IN_FEATS * N_HIDDEN;
    float* W2tf          = (float*)(W1cl + IN_FEATS * N_HIDDEN);  // 40*128 f32
    unsigned short* Hb   = (unsigned short*)(W2tf + N_CLASSES * N_HIDDEN);
                                                          // 50000x128 bf16

    // setup grid: W1 (65536) + W2tf (5120) = 70656 = 276 * 256 exactly
    setup_cvt<<<(IN_FEATS * N_HIDDEN + N_CLASSES * N_HIDDEN) / 256, 256, 0, stream>>>(
        W1, W2, W1ch, W1cl, W2tf);
    megaA<<<NBLK + NBKT, 256, 0, stream>>>(src, dst, histD, histS, X, W1ch, W1cl, Hb);
    p2_local<<<(NBKT + 3) / 4, 256, 0, stream>>>(histD, histS, baseD, baseS, totD, totS);
    p2_small<<<1, 1024, 0, stream>>>(totD, totS, bucket_base, srcb_base, offsets);
    p3_scatter<<<NBLK, 256, 0, stream>>>(src, dst, baseD, baseS, bucket_base, srcb_base,
                                         edata, srcv);
    p4_fused<<<NBKT, 256, 0, stream>>>(srcb_base, srcv, bucket_base, edata,
                                       offsets, norm_src, norm_dst, sorted_src);
    agg1_kernel<<<AGG1_BLOCKS, 256, 0, stream>>>(offsets, sorted_src, Hb, norm_dst,
                                                 norm_src, b1, W2tf, H2u);
    agg2_kernel<<<(N_NODES + 3) / 4, 256, 0, stream>>>(offsets, sorted_src, H2u, norm_dst, b2, out);
}

// Round 10
// 360.830 us; speedup vs baseline: 1.0666x; 1.0382x over previous
//
#include <hip/hip_runtime.h>
#include <hip/hip_bf16.h>

#define N_NODES 50000
#define N_EDGES 1600000
#define IN_FEATS 512
#define N_HIDDEN 128
#define N_CLASSES 40
#define NBKT 782      // ceil(50000/64) buckets of 64 nodes
#define NBLK 800      // partition blocks
#define EPB 2000      // edges per partition block (800*2000 = 1.6M exact)
#define NROWPAD 50048 // 391*128, padded row count for gemm2 A-reads

typedef __attribute__((ext_vector_type(8))) short bf16x8;
typedef __attribute__((ext_vector_type(4))) float f32x4;

__device__ __forceinline__ unsigned short f2bf(float f) {
    unsigned u = __float_as_uint(f);
    u = (u + 0x7FFFu + ((u >> 16) & 1u)) >> 16;   // round-to-nearest-even
    return (unsigned short)u;
}
__device__ __forceinline__ float bf2f(unsigned short h) {
    return __uint_as_float(((unsigned)h) << 16);
}
// packed f32x2 -> bf16x2 (RTNE), lowers to v_cvt_pk_bf16_f32 on gfx950
__device__ __forceinline__ unsigned pk_bf(float a, float b) {
    __hip_bfloat162 h = __float22bfloat162_rn(make_float2(a, b));
    union { __hip_bfloat162 v; unsigned u; } c;
    c.v = h;
    return c.u;   // low 16 = bf(a), high 16 = bf(b)
}

// 8 floats (two float4) -> hi/lo bf16x8 fragments, in registers.
__device__ __forceinline__ void cvt8(float4 a, float4 b, bf16x8& h, bf16x8& l) {
    unsigned h0 = pk_bf(a.x, a.y), h1 = pk_bf(a.z, a.w);
    unsigned h2 = pk_bf(b.x, b.y), h3 = pk_bf(b.z, b.w);
    unsigned l0 = pk_bf(a.x - __uint_as_float(h0 << 16),
                        a.y - __uint_as_float(h0 & 0xffff0000u));
    unsigned l1 = pk_bf(a.z - __uint_as_float(h1 << 16),
                        a.w - __uint_as_float(h1 & 0xffff0000u));
    unsigned l2 = pk_bf(b.x - __uint_as_float(h2 << 16),
                        b.y - __uint_as_float(h2 & 0xffff0000u));
    unsigned l3 = pk_bf(b.z - __uint_as_float(h3 << 16),
                        b.w - __uint_as_float(h3 & 0xffff0000u));
    union U { unsigned u[4]; bf16x8 v; };
    U H; H.u[0] = h0; H.u[1] = h1; H.u[2] = h2; H.u[3] = h3; h = H.v;
    U L; L.u[0] = l0; L.u[1] = l1; L.u[2] = l2; L.u[3] = l3; l = L.v;
}

__device__ __forceinline__ int imin(int a, int b) { return a < b ? a : b; }

// ---------------------------------------------------------------------------
// setup: W1 -> k-chunked bf16 hi/lo [kc][col][ki]; W2 -> transposed [48][128]
__global__ __launch_bounds__(256) void setup_cvt(
    const float* __restrict__ W1, const float* __restrict__ W2,
    unsigned short* __restrict__ W1ch, unsigned short* __restrict__ W1cl,
    unsigned short* __restrict__ W2th, unsigned short* __restrict__ W2tl) {
    int i = blockIdx.x * 256 + threadIdx.x;
    if (i < IN_FEATS * N_HIDDEN) {
        int k = i >> 7, c = i & 127;
        float v = W1[i];
        unsigned short h = f2bf(v);
        int o = (k >> 5) * 4096 + c * 32 + (k & 31);
        W1ch[o] = h;
        W1cl[o] = f2bf(v - bf2f(h));
    } else {
        int j = i - IN_FEATS * N_HIDDEN;    // 0..6143 (grid sized exactly)
        int n = j >> 7, k = j & 127;
        float v = (n < N_CLASSES) ? W2[k * N_CLASSES + n] : 0.f;
        unsigned short h = f2bf(v);
        W2th[n * 128 + k] = h;
        W2tl[n * 128 + k] = f2bf(v - bf2f(h));
    }
}

// ---------------------------------------------------------------------------
// megaA: blocks [0,NBKT) = gemm1 tiles; blocks [NBKT,NBKT+NBLK) = p1_hist.
// gemm1 r7 structure (60us plateau, closed): lane-linear LDS, two chunks per
// barrier, 4 LDS buffers.

#define MFJ(AH, AL, BH, BL, ACC)                                              \
    ACC = __builtin_amdgcn_mfma_f32_16x16x32_bf16(AH, BH, ACC, 0, 0, 0);      \
    ACC = __builtin_amdgcn_mfma_f32_16x16x32_bf16(AH, BL, ACC, 0, 0, 0);      \
    ACC = __builtin_amdgcn_mfma_f32_16x16x32_bf16(AL, BH, ACC, 0, 0, 0);

#define CHUNK_COMPUTE(FRAGBASE, KC)                                           \
    {                                                                         \
        const unsigned short* wk  = wbh + (KC) * 4096;                        \
        const unsigned short* wkl = wbl + (KC) * 4096;                        \
        bf16x8 bh0 = *(const bf16x8*)(wk);                                    \
        bf16x8 bh1 = *(const bf16x8*)(wk + 512);                              \
        bf16x8 bl0 = *(const bf16x8*)(wkl);                                   \
        bf16x8 bl1 = *(const bf16x8*)(wkl + 512);                             \
        const unsigned short* fb = (FRAGBASE);                                \
        bf16x8 ah0 = *(const bf16x8*)(fb + (0 * 64 + lane) * 8);              \
        bf16x8 ah1 = *(const bf16x8*)(fb + (1 * 64 + lane) * 8);              \
        bf16x8 ah2 = *(const bf16x8*)(fb + (2 * 64 + lane) * 8);              \
        bf16x8 ah3 = *(const bf16x8*)(fb + (3 * 64 + lane) * 8);              \
        bf16x8 al0 = *(const bf16x8*)(fb + 2048 + (0 * 64 + lane) * 8);       \
        bf16x8 al1 = *(const bf16x8*)(fb + 2048 + (1 * 64 + lane) * 8);       \
        bf16x8 al2 = *(const bf16x8*)(fb + 2048 + (2 * 64 + lane) * 8);       \
        bf16x8 al3 = *(const bf16x8*)(fb + 2048 + (3 * 64 + lane) * 8);       \
        MFJ(ah0, al0, bh0, bl0, acc[0][0]) MFJ(ah0, al0, bh1, bl1, acc[0][1]) \
        MFJ(ah1, al1, bh0, bl0, acc[1][0]) MFJ(ah1, al1, bh1, bl1, acc[1][1]) \
        MFJ(ah2, al2, bh0, bl0, acc[2][0]) MFJ(ah2, al2, bh1, bl1, acc[2][1]) \
        MFJ(ah3, al3, bh0, bl0, acc[3][0]) MFJ(ah3, al3, bh1, bl1, acc[3][1]) \
    }

__global__ __launch_bounds__(256) void megaA(
    const int* __restrict__ src, const int* __restrict__ dst,
    int* __restrict__ histD, int* __restrict__ histS,
    const float* __restrict__ X, const unsigned short* __restrict__ Wch,
    const unsigned short* __restrict__ Wcl, unsigned short* __restrict__ Hb) {
    __shared__ __align__(16) unsigned char smem[32768];
    const int tid = threadIdx.x;

    if (blockIdx.x >= NBKT) {
        // ---- p1_hist ----
        int* hd = (int*)smem;
        int* hs = hd + NBKT;
        int b = blockIdx.x - NBKT;
        for (int i = tid; i < NBKT; i += 256) { hd[i] = 0; hs[i] = 0; }
        __syncthreads();
        int e0 = b * EPB;
        for (int i = tid; i < EPB; i += 256) {
            atomicAdd(&hd[dst[e0 + i] >> 6], 1);
            atomicAdd(&hs[src[e0 + i] >> 6], 1);
        }
        __syncthreads();
        for (int i = tid; i < NBKT; i += 256) {
            histD[b * NBKT + i] = hd[i];
            histS[b * NBKT + i] = hs[i];
        }
        return;
    }
    // ---- gemm1: 64 rows, split-precision bf16 MFMA, unscaled output ----
    typedef unsigned short ush;
    ush* lds = (ush*)smem;   // set s at + s*8192 ush; within set:
                             // chunkA hi +0, lo +2048; chunkB hi +4096, lo +6144

    const int lane = tid & 63;
    const int wv = tid >> 6;
    const int m = lane & 15;
    const int q = lane >> 4;
    const int q8 = q * 8;
    const int row0 = blockIdx.x * 64;

    const unsigned short* wbh = Wch + (wv * 32 + m) * 32 + q8;
    const unsigned short* wbl = Wcl + (wv * 32 + m) * 32 + q8;

    const int srow = (tid >> 6) * 16 + (tid & 15);      // row within tile
    const int sq8  = ((tid >> 4) & 3) * 8;              // col group * 8
    const float* xp = &X[(size_t)imin(row0 + srow, N_NODES - 1) * IN_FEATS + sq8];

    f32x4 acc[4][2];
#pragma unroll
    for (int i = 0; i < 4; i++)
#pragma unroll
        for (int j = 0; j < 2; j++) acc[i][j] = (f32x4){0.f, 0.f, 0.f, 0.f};

    // prologue: stage pair 0 (chunks 0,1) into set 0; pair 1 X into regs
    {
        float4 c00 = *(const float4*)(xp),      c01 = *(const float4*)(xp + 4);
        float4 c10 = *(const float4*)(xp + 32), c11 = *(const float4*)(xp + 36);
        bf16x8 h, l;
        cvt8(c00, c01, h, l);
        *(bf16x8*)(lds + tid * 8) = h;
        *(bf16x8*)(lds + 2048 + tid * 8) = l;
        cvt8(c10, c11, h, l);
        *(bf16x8*)(lds + 4096 + tid * 8) = h;
        *(bf16x8*)(lds + 6144 + tid * 8) = l;
    }
    float4 a00 = *(const float4*)(xp + 64), a01 = *(const float4*)(xp + 68);
    float4 a10 = *(const float4*)(xp + 96), a11 = *(const float4*)(xp + 100);
    __syncthreads();

    for (int pp = 0; pp < 8; pp++) {
        if (pp < 7) {
            ush* bs = lds + ((pp + 1) & 1) * 8192;
            bf16x8 h, l;
            cvt8(a00, a01, h, l);
            *(bf16x8*)(bs + tid * 8) = h;
            *(bf16x8*)(bs + 2048 + tid * 8) = l;
            cvt8(a10, a11, h, l);
            *(bf16x8*)(bs + 4096 + tid * 8) = h;
            *(bf16x8*)(bs + 6144 + tid * 8) = l;
        }
        if (pp < 6) {
            const float* xq = xp + (pp + 2) * 64;
            a00 = *(const float4*)(xq);      a01 = *(const float4*)(xq + 4);
            a10 = *(const float4*)(xq + 32); a11 = *(const float4*)(xq + 36);
        }
        const ush* br = lds + (pp & 1) * 8192;
        CHUNK_COMPUTE(br,        2 * pp)
        CHUNK_COMPUTE(br + 4096, 2 * pp + 1)
        if (pp < 7) __syncthreads();
    }

#pragma unroll
    for (int i = 0; i < 4; i++) {
#pragma unroll
        for (int r = 0; r < 4; r++) {
            int grow = row0 + i * 16 + q * 4 + r;
            if (grow < N_NODES) {
#pragma unroll
                for (int j = 0; j < 2; j++)
                    Hb[(size_t)grow * N_HIDDEN + wv * 32 + j * 16 + m] = f2bf(acc[i][j][r]);
            }
        }
    }
}

// ---------------------------------------------------------------------------
// P2a: one wave per bucket — parallel scan over the 800-block dimension.
__global__ __launch_bounds__(256) void p2_local(
    const int* __restrict__ histD, const int* __restrict__ histS,
    int* __restrict__ baseD, int* __restrict__ baseS,
    int* __restrict__ totD, int* __restrict__ totS) {
    int wv = threadIdx.x >> 6, lane = threadIdx.x & 63;
    int w = blockIdx.x * 4 + wv;
    if (w >= NBKT) return;
    int runD = 0, runS = 0;
#pragma unroll
    for (int c = 0; c < 13; c++) {
        int blk = c * 64 + lane;
        int vD = 0, vS = 0;
        if (blk < NBLK) {
            vD = histD[blk * NBKT + w];
            vS = histS[blk * NBKT + w];
        }
        int iD = vD, iS = vS;
#pragma unroll
        for (int off = 1; off < 64; off <<= 1) {
            int tD = __shfl_up(iD, off);
            int tS = __shfl_up(iS, off);
            if (lane >= off) { iD += tD; iS += tS; }
        }
        if (blk < NBLK) {
            baseD[blk * NBKT + w] = runD + iD - vD;
            baseS[blk * NBKT + w] = runS + iS - vS;
        }
        runD += __shfl(iD, 63);
        runS += __shfl(iS, 63);
    }
    if (lane == 0) { totD[w] = runD; totS[w] = runS; }
}

// P2b: single-block scan over the 782 bucket totals only.
__global__ __launch_bounds__(1024) void p2_small(
    const int* __restrict__ totD, const int* __restrict__ totS,
    int* __restrict__ bucket_base, int* __restrict__ srcb_base,
    int* __restrict__ offsets) {
    __shared__ int part[1024];
    int t = threadIdx.x;
    int v = (t < NBKT) ? totD[t] : 0;
    part[t] = v;
    __syncthreads();
    for (int off = 1; off < 1024; off <<= 1) {
        int x = (t >= off) ? part[t - off] : 0;
        __syncthreads();
        part[t] += x;
        __syncthreads();
    }
    if (t < NBKT) bucket_base[t] = part[t] - v;
    if (t == 0) { bucket_base[NBKT] = N_EDGES; offsets[N_NODES] = N_EDGES; }
    __syncthreads();
    v = (t < NBKT) ? totS[t] : 0;
    part[t] = v;
    __syncthreads();
    for (int off = 1; off < 1024; off <<= 1) {
        int x = (t >= off) ? part[t - off] : 0;
        __syncthreads();
        part[t] += x;
        __syncthreads();
    }
    if (t < NBKT) srcb_base[t] = part[t] - v;
    if (t == 0) srcb_base[NBKT] = N_EDGES;
}

// ---------------------------------------------------------------------------
// P3: scatter edges into bucket-partitioned arrays via LDS cursors.
__global__ __launch_bounds__(256) void p3_scatter(
    const int* __restrict__ src, const int* __restrict__ dst,
    const int* __restrict__ baseD, const int* __restrict__ baseS,
    const int* __restrict__ bucket_base, const int* __restrict__ srcb_base,
    unsigned int* __restrict__ edata, unsigned char* __restrict__ srcv) {
    __shared__ int curD[NBKT], curS[NBKT];
    int t = threadIdx.x, b = blockIdx.x;
    for (int i = t; i < NBKT; i += 256) {
        curD[i] = bucket_base[i] + baseD[b * NBKT + i];
        curS[i] = srcb_base[i] + baseS[b * NBKT + i];
    }
    __syncthreads();
    int e0 = b * EPB;
    for (int i = t; i < EPB; i += 256) {
        int s = src[e0 + i], d = dst[e0 + i];
        int slotD = atomicAdd(&curD[d >> 6], 1);
        edata[slotD] = (unsigned)s | ((unsigned)(d & 63) << 16);
        int slotS = atomicAdd(&curS[s >> 6], 1);
        srcv[slotS] = (unsigned char)(s & 63);
    }
}

// ---------------------------------------------------------------------------
// P4 fused: src-side count -> norm_src; dst-side count+scatter -> offsets,
// norm_dst, sorted_src (ushort: node ids < 65536). One block per bucket.
__global__ __launch_bounds__(256) void p4_fused(
    const int* __restrict__ srcb_base, const unsigned char* __restrict__ srcv,
    const int* __restrict__ bucket_base, const unsigned int* __restrict__ edata,
    int* __restrict__ offsets, float* __restrict__ norm_src,
    float* __restrict__ norm_dst, unsigned short* __restrict__ sorted_src) {
    __shared__ int cntS[64], cntD[64], cur[64];
    int t = threadIdx.x, b = blockIdx.x;
    if (t < 64) { cntS[t] = 0; cntD[t] = 0; }
    __syncthreads();
    int s0 = srcb_base[b], s1 = srcb_base[b + 1];
    for (int i = s0 + t; i < s1; i += 256) atomicAdd(&cntS[srcv[i]], 1);
    int d0 = bucket_base[b], d1 = bucket_base[b + 1];
    for (int i = d0 + t; i < d1; i += 256)
        atomicAdd(&cntD[(edata[i] >> 16) & 63], 1);
    __syncthreads();
    if (t == 0) {
        int run = 0;
        for (int i = 0; i < 64; i++) { cur[i] = run; run += cntD[i]; }
    }
    __syncthreads();
    if (t < 64) {
        int node = b * 64 + t;
        if (node < N_NODES) {
            norm_src[node] = rsqrtf(fmaxf((float)cntS[t], 1.0f));
            offsets[node] = d0 + cur[t];
            norm_dst[node] = rsqrtf(fmaxf((float)cntD[t], 1.0f));
        }
    }
    __syncthreads();
    for (int i = d0 + t; i < d1; i += 256) {
        unsigned e = edata[i];
        int slot = atomicAdd(&cur[(e >> 16) & 63], 1);
        sorted_src[d0 + slot] = (unsigned short)(e & 0xFFFFu);
    }
}

// ---------------------------------------------------------------------------
// agg1 (r10): one wave per dst node; 32 EDGES IN FLIGHT (8 per quad,
// statically unrolled -> registers) to double gather MLP; identical
// per-lane accumulation order to the old 16-edge loop. Then 16/4/1 tails,
// xor-16/32 butterfly, fused norm_dst+bias+relu, H1 bf16 hi/lo out.
#define FMA8(W, NS)                                                   \
    acc0 = fmaf(__uint_as_float((W).x << 16), NS, acc0);              \
    acc1 = fmaf(__uint_as_float((W).x & 0xffff0000u), NS, acc1);      \
    acc2 = fmaf(__uint_as_float((W).y << 16), NS, acc2);              \
    acc3 = fmaf(__uint_as_float((W).y & 0xffff0000u), NS, acc3);      \
    acc4 = fmaf(__uint_as_float((W).z << 16), NS, acc4);              \
    acc5 = fmaf(__uint_as_float((W).z & 0xffff0000u), NS, acc5);      \
    acc6 = fmaf(__uint_as_float((W).w << 16), NS, acc6);              \
    acc7 = fmaf(__uint_as_float((W).w & 0xffff0000u), NS, acc7);

__global__ __launch_bounds__(256) void agg1_kernel(
    const int* __restrict__ offsets, const unsigned short* __restrict__ sorted_src,
    const unsigned short* __restrict__ Hb, const float* __restrict__ norm_dst,
    const float* __restrict__ norm_src, const float* __restrict__ b1,
    unsigned short* __restrict__ H1h, unsigned short* __restrict__ H1l) {
    int wid = (blockIdx.x * 256 + threadIdx.x) >> 6;
    int lane = threadIdx.x & 63;
    if (wid >= N_NODES) return;
    int start = offsets[wid], end = offsets[wid + 1];
    int quad = lane >> 4;
    int c8 = (lane & 15) * 8;
    float acc0 = 0.f, acc1 = 0.f, acc2 = 0.f, acc3 = 0.f;
    float acc4 = 0.f, acc5 = 0.f, acc6 = 0.f, acc7 = 0.f;
    int base = start;
    for (; base + 32 <= end; base += 32) {
        int e[8];
#pragma unroll
        for (int j = 0; j < 8; j++) e[j] = sorted_src[base + j * 4 + quad];
        float n[8];
#pragma unroll
        for (int j = 0; j < 8; j++) n[j] = norm_src[e[j]];
        uint4 w[8];
#pragma unroll
        for (int j = 0; j < 8; j++)
            w[j] = *(const uint4*)&Hb[(size_t)e[j] * N_HIDDEN + c8];
#pragma unroll
        for (int j = 0; j < 8; j++) { FMA8(w[j], n[j]); }
    }
    for (; base + 16 <= end; base += 16) {
        int e0 = sorted_src[base + quad];
        int e1 = sorted_src[base + 4 + quad];
        int e2 = sorted_src[base + 8 + quad];
        int e3 = sorted_src[base + 12 + quad];
        float n0 = norm_src[e0], n1 = norm_src[e1];
        float n2 = norm_src[e2], n3 = norm_src[e3];
        uint4 w0 = *(const uint4*)&Hb[(size_t)e0 * N_HIDDEN + c8];
        uint4 w1 = *(const uint4*)&Hb[(size_t)e1 * N_HIDDEN + c8];
        uint4 w2 = *(const uint4*)&Hb[(size_t)e2 * N_HIDDEN + c8];
        uint4 w3 = *(const uint4*)&Hb[(size_t)e3 * N_HIDDEN + c8];
        FMA8(w0, n0);
        FMA8(w1, n1);
        FMA8(w2, n2);
        FMA8(w3, n3);
    }
    for (; base + 4 <= end; base += 4) {
        int e = sorted_src[base + quad];
        float n = norm_src[e];
        uint4 w = *(const uint4*)&Hb[(size_t)e * N_HIDDEN + c8];
        FMA8(w, n);
    }
    int rem = end - base;
    if (quad < rem) {
        int e = sorted_src[base + quad];
        float n = norm_src[e];
        uint4 w = *(const uint4*)&Hb[(size_t)e * N_HIDDEN + c8];
        FMA8(w, n);
    }
    acc0 += __shfl_xor(acc0, 16); acc0 += __shfl_xor(acc0, 32);
    acc1 += __shfl_xor(acc1, 16); acc1 += __shfl_xor(acc1, 32);
    acc2 += __shfl_xor(acc2, 16); acc2 += __shfl_xor(acc2, 32);
    acc3 += __shfl_xor(acc3, 16); acc3 += __shfl_xor(acc3, 32);
    acc4 += __shfl_xor(acc4, 16); acc4 += __shfl_xor(acc4, 32);
    acc5 += __shfl_xor(acc5, 16); acc5 += __shfl_xor(acc5, 32);
    acc6 += __shfl_xor(acc6, 16); acc6 += __shfl_xor(acc6, 32);
    acc7 += __shfl_xor(acc7, 16); acc7 += __shfl_xor(acc7, 32);
    if (quad == 0) {
        float nd = norm_dst[wid];
        float ns = norm_src[wid];
        float4 ba = *(const float4*)&b1[c8];
        float4 bb = *(const float4*)&b1[c8 + 4];
        float o[8];
        o[0] = fmaxf(acc0 * nd + ba.x, 0.f) * ns;
        o[1] = fmaxf(acc1 * nd + ba.y, 0.f) * ns;
        o[2] = fmaxf(acc2 * nd + ba.z, 0.f) * ns;
        o[3] = fmaxf(acc3 * nd + ba.w, 0.f) * ns;
        o[4] = fmaxf(acc4 * nd + bb.x, 0.f) * ns;
        o[5] = fmaxf(acc5 * nd + bb.y, 0.f) * ns;
        o[6] = fmaxf(acc6 * nd + bb.z, 0.f) * ns;
        o[7] = fmaxf(acc7 * nd + bb.w, 0.f) * ns;
        unsigned short hh[8], ll[8];
#pragma unroll
        for (int t = 0; t < 8; t++) {
            hh[t] = f2bf(o[t]);
            ll[t] = f2bf(o[t] - bf2f(hh[t]));
        }
        uint4 ph = make_uint4((unsigned)hh[0] | ((unsigned)hh[1] << 16),
                              (unsigned)hh[2] | ((unsigned)hh[3] << 16),
                              (unsigned)hh[4] | ((unsigned)hh[5] << 16),
                              (unsigned)hh[6] | ((unsigned)hh[7] << 16));
        uint4 pl = make_uint4((unsigned)ll[0] | ((unsigned)ll[1] << 16),
                              (unsigned)ll[2] | ((unsigned)ll[3] << 16),
                              (unsigned)ll[4] | ((unsigned)ll[5] << 16),
                              (unsigned)ll[6] | ((unsigned)ll[7] << 16));
        *(uint4*)&H1h[(size_t)wid * N_HIDDEN + c8] = ph;
        *(uint4*)&H1l[(size_t)wid * N_HIDDEN + c8] = pl;
    }
}

// ---------------------------------------------------------------------------
// GEMM2 via bf16 MFMA: H2u[n][0:40] = H1n @ W2, PACKED hi|lo bf16 in u32
// (full f32 precision to 2^-17 rel), 48-dword rows for 16B-aligned gathers.
__global__ __launch_bounds__(256) void gemm2_kernel(
    const unsigned short* __restrict__ H1h, const unsigned short* __restrict__ H1l,
    const unsigned short* __restrict__ W2th, const unsigned short* __restrict__ W2tl,
    unsigned int* __restrict__ H2u) {
    __shared__ __align__(16) unsigned short Bh[48][136];
    __shared__ __align__(16) unsigned short Bl[48][136];
    const int tid = threadIdx.x;
    for (int i = tid; i < 48 * 16; i += 256) {
        int n = i >> 4, kq = (i & 15) * 8;
        *(uint4*)&Bh[n][kq] = *(const uint4*)&W2th[n * 128 + kq];
        *(uint4*)&Bl[n][kq] = *(const uint4*)&W2tl[n * 128 + kq];
    }
    __syncthreads();
    const int lane = tid & 63;
    const int wave = tid >> 6;
    const int m = lane & 15;
    const int q = lane >> 4;
    const int row0 = blockIdx.x * 128 + wave * 32;

    f32x4 acc[2][3];
#pragma unroll
    for (int i = 0; i < 2; i++)
#pragma unroll
        for (int j = 0; j < 3; j++) acc[i][j] = (f32x4){0.f, 0.f, 0.f, 0.f};

#pragma unroll
    for (int kc = 0; kc < 4; kc++) {
        bf16x8 bh[3], bl[3];
#pragma unroll
        for (int j = 0; j < 3; j++) {
            bh[j] = *(const bf16x8*)&Bh[j * 16 + m][kc * 32 + q * 8];
            bl[j] = *(const bf16x8*)&Bl[j * 16 + m][kc * 32 + q * 8];
        }
#pragma unroll
        for (int i = 0; i < 2; i++) {
            size_t ro = (size_t)(row0 + i * 16 + m) * N_HIDDEN + kc * 32 + q * 8;
            bf16x8 ah = *(const bf16x8*)&H1h[ro];
            bf16x8 al = *(const bf16x8*)&H1l[ro];
#pragma unroll
            for (int j = 0; j < 3; j++) {
                acc[i][j] = __builtin_amdgcn_mfma_f32_16x16x32_bf16(ah, bh[j], acc[i][j], 0, 0, 0);
                acc[i][j] = __builtin_amdgcn_mfma_f32_16x16x32_bf16(ah, bl[j], acc[i][j], 0, 0, 0);
                acc[i][j] = __builtin_amdgcn_mfma_f32_16x16x32_bf16(al, bh[j], acc[i][j], 0, 0, 0);
            }
        }
    }
#pragma unroll
    for (int i = 0; i < 2; i++) {
#pragma unroll
        for (int r = 0; r < 4; r++) {
            int row = row0 + i * 16 + q * 4 + r;
            if (row < N_NODES) {
#pragma unroll
                for (int j = 0; j < 3; j++) {
                    int col = j * 16 + m;
                    if (col < N_CLASSES) {
                        float v = acc[i][j][r];
                        unsigned short h = f2bf(v);
                        unsigned short l = f2bf(v - bf2f(h));
                        H2u[(size_t)row * 48 + col] = ((unsigned)h << 16) | (unsigned)l;
                    }
                }
            }
        }
    }
}

// ---------------------------------------------------------------------------
// agg2 (r10): one wave per dst node; 32 edges in flight (8 uint4/quad,
// statically unrolled), packed hi|lo bf16 reconstruction, butterfly reduce.
#define ACC4(V)                                                               \
    acc.x += __uint_as_float((V).x & 0xffff0000u) + __uint_as_float((V).x << 16); \
    acc.y += __uint_as_float((V).y & 0xffff0000u) + __uint_as_float((V).y << 16); \
    acc.z += __uint_as_float((V).z & 0xffff0000u) + __uint_as_float((V).z << 16); \
    acc.w += __uint_as_float((V).w & 0xffff0000u) + __uint_as_float((V).w << 16);

__global__ __launch_bounds__(256) void agg2_kernel(
    const int* __restrict__ offsets, const unsigned short* __restrict__ sorted_src,
    const unsigned int* __restrict__ H2u, const float* __restrict__ norm_dst,
    const float* __restrict__ b2, float* __restrict__ OUT) {
    int wid = (blockIdx.x * 256 + threadIdx.x) >> 6;
    int lane = threadIdx.x & 63;
    if (wid >= N_NODES) return;
    int start = offsets[wid], end = offsets[wid + 1];
    int quad = lane >> 4;
    int c4 = (lane & 15) * 4;
    bool active = c4 < N_CLASSES;
    float4 acc = make_float4(0.f, 0.f, 0.f, 0.f);
    int base = start;
    for (; base + 32 <= end; base += 32) {
        int e[8];
#pragma unroll
        for (int j = 0; j < 8; j++) e[j] = sorted_src[base + j * 4 + quad];
        if (active) {
            uint4 v[8];
#pragma unroll
            for (int j = 0; j < 8; j++)
                v[j] = *(const uint4*)&H2u[(size_t)e[j] * 48 + c4];
#pragma unroll
            for (int j = 0; j < 8; j++) { ACC4(v[j]); }
        }
    }
    for (; base + 16 <= end; base += 16) {
        int e0 = sorted_src[base + quad];
        int e1 = sorted_src[base + 4 + quad];
        int e2 = sorted_src[base + 8 + quad];
        int e3 = sorted_src[base + 12 + quad];
        if (active) {
            uint4 v0 = *(const uint4*)&H2u[(size_t)e0 * 48 + c4];
            uint4 v1 = *(const uint4*)&H2u[(size_t)e1 * 48 + c4];
            uint4 v2 = *(const uint4*)&H2u[(size_t)e2 * 48 + c4];
            uint4 v3 = *(const uint4*)&H2u[(size_t)e3 * 48 + c4];
            ACC4(v0); ACC4(v1); ACC4(v2); ACC4(v3);
        }
    }
    for (; base + 4 <= end; base += 4) {
        int e = sorted_src[base + quad];
        if (active) {
            uint4 v = *(const uint4*)&H2u[(size_t)e * 48 + c4];
            ACC4(v);
        }
    }
    int rem = end - base;
    if (quad < rem && active) {
        int e = sorted_src[base + quad];
        uint4 v = *(const uint4*)&H2u[(size_t)e * 48 + c4];
        ACC4(v);
    }
    acc.x += __shfl_xor(acc.x, 16); acc.x += __shfl_xor(acc.x, 32);
    acc.y += __shfl_xor(acc.y, 16); acc.y += __shfl_xor(acc.y, 32);
    acc.z += __shfl_xor(acc.z, 16); acc.z += __shfl_xor(acc.z, 32);
    acc.w += __shfl_xor(acc.w, 16); acc.w += __shfl_xor(acc.w, 32);
    if (lane < 10) {
        float nd = norm_dst[wid];
        float4 b = *(const float4*)&b2[lane * 4];
        acc.x = acc.x * nd + b.x;
        acc.y = acc.y * nd + b.y;
        acc.z = acc.z * nd + b.z;
        acc.w = acc.w * nd + b.w;
        *(float4*)&OUT[(size_t)wid * N_CLASSES + lane * 4] = acc;
    }
}

// ---------------------------------------------------------------------------
extern "C" void kernel_launch(void* const* d_in, const int* in_sizes, int n_in,
                              void* d_out, int out_size, void* d_ws, size_t ws_size,
                              hipStream_t stream) {
    const float* X   = (const float*)d_in[0];
    const float* W1  = (const float*)d_in[1];
    const float* b1  = (const float*)d_in[2];
    const float* W2  = (const float*)d_in[3];
    const float* b2  = (const float*)d_in[4];
    const int*   src = (const int*)d_in[5];
    const int*   dst = (const int*)d_in[6];
    float* out = (float*)d_out;

    // workspace layout (4B units). regionA time-shared:
    //   phase 1: histD|histS|baseD|baseS|totD|totS      [dead after p3]
    //   phase 3: H2u packed u32 50000x48 (2.4M dwords)  [written at gemm2]
    // Hb has its own region (written by megaA while phase-1 data live).
    float* norm_src   = (float*)d_ws;                     // 50000
    float* norm_dst   = norm_src + N_NODES;               // 50000
    int*   offsets    = (int*)(norm_dst + N_NODES);       // 50016 (incl pad)
    int*   bucket_base = offsets + N_NODES + 16;          // 800
    int*   srcb_base  = bucket_base + 800;                // 800
    unsigned int* edata = (unsigned int*)(srcb_base + 800);       // 1.6M
    unsigned char* srcv = (unsigned char*)(edata + N_EDGES);      // 400K dwords
    unsigned short* sorted_src =
        (unsigned short*)((int*)(edata + N_EDGES) + 400000);      // 1.6M ushort
    int*   regionA    = (int*)(edata + N_EDGES) + 400000 + 800000; // 3.2M dwords
    int*   histD      = regionA;
    int*   histS      = regionA + 625600;
    int*   baseD      = regionA + 1251200;
    int*   baseS      = regionA + 1876800;
    int*   totD       = regionA + 2502400;                // 800
    int*   totS       = regionA + 2503200;                // 800
    unsigned int* H2u = (unsigned int*)regionA;           // phase 3 (2.4M)
    unsigned short* H1h = (unsigned short*)(regionA + 3200000);   // 50048x128 bf16
    unsigned short* H1l = H1h + (size_t)NROWPAD * N_HIDDEN;
    unsigned short* W1ch = H1l + (size_t)NROWPAD * N_HIDDEN;      // k-chunked 512*128
    unsigned short* W1cl = W1ch + IN_FEATS * N_HIDDEN;
    unsigned short* W2th = W1cl + IN_FEATS * N_HIDDEN;            // 48*128
    unsigned short* W2tl = W2th + 48 * 128;
    unsigned short* Hb   = W2tl + 48 * 128;               // 50000x128 bf16 (own region)

    setup_cvt<<<(IN_FEATS * N_HIDDEN + 48 * 128) / 256, 256, 0, stream>>>(
        W1, W2, W1ch, W1cl, W2th, W2tl);
    megaA<<<NBLK + NBKT, 256, 0, stream>>>(src, dst, histD, histS, X, W1ch, W1cl, Hb);
    p2_local<<<(NBKT + 3) / 4, 256, 0, stream>>>(histD, histS, baseD, baseS, totD, totS);
    p2_small<<<1, 1024, 0, stream>>>(totD, totS, bucket_base, srcb_base, offsets);
    p3_scatter<<<NBLK, 256, 0, stream>>>(src, dst, baseD, baseS, bucket_base, srcb_base,
                                         edata, srcv);
    p4_fused<<<NBKT, 256, 0, stream>>>(srcb_base, srcv, bucket_base, edata,
                                       offsets, norm_src, norm_dst, sorted_src);
    agg1_kernel<<<(N_NODES + 3) / 4, 256, 0, stream>>>(offsets, sorted_src, Hb, norm_dst,
                                                       norm_src, b1, H1h, H1l);
    gemm2_kernel<<<(N_NODES + 127) / 128, 256, 0, stream>>>(H1h, H1l, W2th, W2tl, H2u);
    agg2_kernel<<<(N_NODES + 3) / 4, 256, 0, stream>>>(offsets, sorted_src, H2u, norm_dst, b2, out);
}

// Round 11
// 355.087 us; speedup vs baseline: 1.0838x; 1.0162x over previous
//
#include <hip/hip_runtime.h>
#include <hip/hip_bf16.h>

#define N_NODES 50000
#define N_EDGES 1600000
#define IN_FEATS 512
#define N_HIDDEN 128
#define N_CLASSES 40
#define NBKT 782      // ceil(50000/64) buckets of 64 nodes
#define NBLK 800      // partition blocks
#define EPB 2000      // edges per partition block (800*2000 = 1.6M exact)
#define NROWPAD 50048 // 391*128, padded row count for gemm2 A-reads

typedef __attribute__((ext_vector_type(8))) short bf16x8;
typedef __attribute__((ext_vector_type(4))) float f32x4;

__device__ __forceinline__ unsigned short f2bf(float f) {
    unsigned u = __float_as_uint(f);
    u = (u + 0x7FFFu + ((u >> 16) & 1u)) >> 16;   // round-to-nearest-even
    return (unsigned short)u;
}
__device__ __forceinline__ float bf2f(unsigned short h) {
    return __uint_as_float(((unsigned)h) << 16);
}
// packed f32x2 -> bf16x2 (RTNE), lowers to v_cvt_pk_bf16_f32 on gfx950
__device__ __forceinline__ unsigned pk_bf(float a, float b) {
    __hip_bfloat162 h = __float22bfloat162_rn(make_float2(a, b));
    union { __hip_bfloat162 v; unsigned u; } c;
    c.v = h;
    return c.u;   // low 16 = bf(a), high 16 = bf(b)
}

// 8 floats (two float4) -> hi/lo bf16x8 fragments, in registers.
__device__ __forceinline__ void cvt8(float4 a, float4 b, bf16x8& h, bf16x8& l) {
    unsigned h0 = pk_bf(a.x, a.y), h1 = pk_bf(a.z, a.w);
    unsigned h2 = pk_bf(b.x, b.y), h3 = pk_bf(b.z, b.w);
    unsigned l0 = pk_bf(a.x - __uint_as_float(h0 << 16),
                        a.y - __uint_as_float(h0 & 0xffff0000u));
    unsigned l1 = pk_bf(a.z - __uint_as_float(h1 << 16),
                        a.w - __uint_as_float(h1 & 0xffff0000u));
    unsigned l2 = pk_bf(b.x - __uint_as_float(h2 << 16),
                        b.y - __uint_as_float(h2 & 0xffff0000u));
    unsigned l3 = pk_bf(b.z - __uint_as_float(h3 << 16),
                        b.w - __uint_as_float(h3 & 0xffff0000u));
    union U { unsigned u[4]; bf16x8 v; };
    U H; H.u[0] = h0; H.u[1] = h1; H.u[2] = h2; H.u[3] = h3; h = H.v;
    U L; L.u[0] = l0; L.u[1] = l1; L.u[2] = l2; L.u[3] = l3; l = L.v;
}

__device__ __forceinline__ int imin(int a, int b) { return a < b ? a : b; }

// ---------------------------------------------------------------------------
// setup: W1 -> k-chunked bf16 hi/lo [kc][col][ki]; W2 -> transposed [48][128]
__global__ __launch_bounds__(256) void setup_cvt(
    const float* __restrict__ W1, const float* __restrict__ W2,
    unsigned short* __restrict__ W1ch, unsigned short* __restrict__ W1cl,
    unsigned short* __restrict__ W2th, unsigned short* __restrict__ W2tl) {
    int i = blockIdx.x * 256 + threadIdx.x;
    if (i < IN_FEATS * N_HIDDEN) {
        int k = i >> 7, c = i & 127;
        float v = W1[i];
        unsigned short h = f2bf(v);
        int o = (k >> 5) * 4096 + c * 32 + (k & 31);
        W1ch[o] = h;
        W1cl[o] = f2bf(v - bf2f(h));
    } else {
        int j = i - IN_FEATS * N_HIDDEN;    // 0..6143 (grid sized exactly)
        int n = j >> 7, k = j & 127;
        float v = (n < N_CLASSES) ? W2[k * N_CLASSES + n] : 0.f;
        unsigned short h = f2bf(v);
        W2th[n * 128 + k] = h;
        W2tl[n * 128 + k] = f2bf(v - bf2f(h));
    }
}

// ---------------------------------------------------------------------------
// megaA: blocks [0,NBKT) = gemm1 tiles; blocks [NBKT,NBKT+NBLK) = p1_hist.
// gemm1 r7 structure (60us plateau, closed): lane-linear LDS, two chunks per
// barrier, 4 LDS buffers.

#define MFJ(AH, AL, BH, BL, ACC)                                              \
    ACC = __builtin_amdgcn_mfma_f32_16x16x32_bf16(AH, BH, ACC, 0, 0, 0);      \
    ACC = __builtin_amdgcn_mfma_f32_16x16x32_bf16(AH, BL, ACC, 0, 0, 0);      \
    ACC = __builtin_amdgcn_mfma_f32_16x16x32_bf16(AL, BH, ACC, 0, 0, 0);

#define CHUNK_COMPUTE(FRAGBASE, KC)                                           \
    {                                                                         \
        const unsigned short* wk  = wbh + (KC) * 4096;                        \
        const unsigned short* wkl = wbl + (KC) * 4096;                        \
        bf16x8 bh0 = *(const bf16x8*)(wk);                                    \
        bf16x8 bh1 = *(const bf16x8*)(wk + 512);                              \
        bf16x8 bl0 = *(const bf16x8*)(wkl);                                   \
        bf16x8 bl1 = *(const bf16x8*)(wkl + 512);                             \
        const unsigned short* fb = (FRAGBASE);                                \
        bf16x8 ah0 = *(const bf16x8*)(fb + (0 * 64 + lane) * 8);              \
        bf16x8 ah1 = *(const bf16x8*)(fb + (1 * 64 + lane) * 8);              \
        bf16x8 ah2 = *(const bf16x8*)(fb + (2 * 64 + lane) * 8);              \
        bf16x8 ah3 = *(const bf16x8*)(fb + (3 * 64 + lane) * 8);              \
        bf16x8 al0 = *(const bf16x8*)(fb + 2048 + (0 * 64 + lane) * 8);       \
        bf16x8 al1 = *(const bf16x8*)(fb + 2048 + (1 * 64 + lane) * 8);       \
        bf16x8 al2 = *(const bf16x8*)(fb + 2048 + (2 * 64 + lane) * 8);       \
        bf16x8 al3 = *(const bf16x8*)(fb + 2048 + (3 * 64 + lane) * 8);       \
        MFJ(ah0, al0, bh0, bl0, acc[0][0]) MFJ(ah0, al0, bh1, bl1, acc[0][1]) \
        MFJ(ah1, al1, bh0, bl0, acc[1][0]) MFJ(ah1, al1, bh1, bl1, acc[1][1]) \
        MFJ(ah2, al2, bh0, bl0, acc[2][0]) MFJ(ah2, al2, bh1, bl1, acc[2][1]) \
        MFJ(ah3, al3, bh0, bl0, acc[3][0]) MFJ(ah3, al3, bh1, bl1, acc[3][1]) \
    }

__global__ __launch_bounds__(256) void megaA(
    const int* __restrict__ src, const int* __restrict__ dst,
    int* __restrict__ histD, int* __restrict__ histS,
    const float* __restrict__ X, const unsigned short* __restrict__ Wch,
    const unsigned short* __restrict__ Wcl, unsigned short* __restrict__ Hb) {
    __shared__ __align__(16) unsigned char smem[32768];
    const int tid = threadIdx.x;

    if (blockIdx.x >= NBKT) {
        // ---- p1_hist ----
        int* hd = (int*)smem;
        int* hs = hd + NBKT;
        int b = blockIdx.x - NBKT;
        for (int i = tid; i < NBKT; i += 256) { hd[i] = 0; hs[i] = 0; }
        __syncthreads();
        int e0 = b * EPB;
        for (int i = tid; i < EPB; i += 256) {
            atomicAdd(&hd[dst[e0 + i] >> 6], 1);
            atomicAdd(&hs[src[e0 + i] >> 6], 1);
        }
        __syncthreads();
        for (int i = tid; i < NBKT; i += 256) {
            histD[b * NBKT + i] = hd[i];
            histS[b * NBKT + i] = hs[i];
        }
        return;
    }
    // ---- gemm1: 64 rows, split-precision bf16 MFMA, unscaled output ----
    typedef unsigned short ush;
    ush* lds = (ush*)smem;   // set s at + s*8192 ush; within set:
                             // chunkA hi +0, lo +2048; chunkB hi +4096, lo +6144

    const int lane = tid & 63;
    const int wv = tid >> 6;
    const int m = lane & 15;
    const int q = lane >> 4;
    const int q8 = q * 8;
    const int row0 = blockIdx.x * 64;

    const unsigned short* wbh = Wch + (wv * 32 + m) * 32 + q8;
    const unsigned short* wbl = Wcl + (wv * 32 + m) * 32 + q8;

    const int srow = (tid >> 6) * 16 + (tid & 15);      // row within tile
    const int sq8  = ((tid >> 4) & 3) * 8;              // col group * 8
    const float* xp = &X[(size_t)imin(row0 + srow, N_NODES - 1) * IN_FEATS + sq8];

    f32x4 acc[4][2];
#pragma unroll
    for (int i = 0; i < 4; i++)
#pragma unroll
        for (int j = 0; j < 2; j++) acc[i][j] = (f32x4){0.f, 0.f, 0.f, 0.f};

    // prologue: stage pair 0 (chunks 0,1) into set 0; pair 1 X into regs
    {
        float4 c00 = *(const float4*)(xp),      c01 = *(const float4*)(xp + 4);
        float4 c10 = *(const float4*)(xp + 32), c11 = *(const float4*)(xp + 36);
        bf16x8 h, l;
        cvt8(c00, c01, h, l);
        *(bf16x8*)(lds + tid * 8) = h;
        *(bf16x8*)(lds + 2048 + tid * 8) = l;
        cvt8(c10, c11, h, l);
        *(bf16x8*)(lds + 4096 + tid * 8) = h;
        *(bf16x8*)(lds + 6144 + tid * 8) = l;
    }
    float4 a00 = *(const float4*)(xp + 64), a01 = *(const float4*)(xp + 68);
    float4 a10 = *(const float4*)(xp + 96), a11 = *(const float4*)(xp + 100);
    __syncthreads();

    for (int pp = 0; pp < 8; pp++) {
        if (pp < 7) {
            ush* bs = lds + ((pp + 1) & 1) * 8192;
            bf16x8 h, l;
            cvt8(a00, a01, h, l);
            *(bf16x8*)(bs + tid * 8) = h;
            *(bf16x8*)(bs + 2048 + tid * 8) = l;
            cvt8(a10, a11, h, l);
            *(bf16x8*)(bs + 4096 + tid * 8) = h;
            *(bf16x8*)(bs + 6144 + tid * 8) = l;
        }
        if (pp < 6) {
            const float* xq = xp + (pp + 2) * 64;
            a00 = *(const float4*)(xq);      a01 = *(const float4*)(xq + 4);
            a10 = *(const float4*)(xq + 32); a11 = *(const float4*)(xq + 36);
        }
        const ush* br = lds + (pp & 1) * 8192;
        CHUNK_COMPUTE(br,        2 * pp)
        CHUNK_COMPUTE(br + 4096, 2 * pp + 1)
        if (pp < 7) __syncthreads();
    }

#pragma unroll
    for (int i = 0; i < 4; i++) {
#pragma unroll
        for (int r = 0; r < 4; r++) {
            int grow = row0 + i * 16 + q * 4 + r;
            if (grow < N_NODES) {
#pragma unroll
                for (int j = 0; j < 2; j++)
                    Hb[(size_t)grow * N_HIDDEN + wv * 32 + j * 16 + m] = f2bf(acc[i][j][r]);
            }
        }
    }
}

// ---------------------------------------------------------------------------
// P2a: one wave per bucket — parallel scan over the 800-block dimension.
__global__ __launch_bounds__(256) void p2_local(
    const int* __restrict__ histD, const int* __restrict__ histS,
    int* __restrict__ baseD, int* __restrict__ baseS,
    int* __restrict__ totD, int* __restrict__ totS) {
    int wv = threadIdx.x >> 6, lane = threadIdx.x & 63;
    int w = blockIdx.x * 4 + wv;
    if (w >= NBKT) return;
    int runD = 0, runS = 0;
#pragma unroll
    for (int c = 0; c < 13; c++) {
        int blk = c * 64 + lane;
        int vD = 0, vS = 0;
        if (blk < NBLK) {
            vD = histD[blk * NBKT + w];
            vS = histS[blk * NBKT + w];
        }
        int iD = vD, iS = vS;
#pragma unroll
        for (int off = 1; off < 64; off <<= 1) {
            int tD = __shfl_up(iD, off);
            int tS = __shfl_up(iS, off);
            if (lane >= off) { iD += tD; iS += tS; }
        }
        if (blk < NBLK) {
            baseD[blk * NBKT + w] = runD + iD - vD;
            baseS[blk * NBKT + w] = runS + iS - vS;
        }
        runD += __shfl(iD, 63);
        runS += __shfl(iS, 63);
    }
    if (lane == 0) { totD[w] = runD; totS[w] = runS; }
}

// P2b: single-block scan over the 782 bucket totals only.
__global__ __launch_bounds__(1024) void p2_small(
    const int* __restrict__ totD, const int* __restrict__ totS,
    int* __restrict__ bucket_base, int* __restrict__ srcb_base,
    int* __restrict__ offsets) {
    __shared__ int part[1024];
    int t = threadIdx.x;
    int v = (t < NBKT) ? totD[t] : 0;
    part[t] = v;
    __syncthreads();
    for (int off = 1; off < 1024; off <<= 1) {
        int x = (t >= off) ? part[t - off] : 0;
        __syncthreads();
        part[t] += x;
        __syncthreads();
    }
    if (t < NBKT) bucket_base[t] = part[t] - v;
    if (t == 0) { bucket_base[NBKT] = N_EDGES; offsets[N_NODES] = N_EDGES; }
    __syncthreads();
    v = (t < NBKT) ? totS[t] : 0;
    part[t] = v;
    __syncthreads();
    for (int off = 1; off < 1024; off <<= 1) {
        int x = (t >= off) ? part[t - off] : 0;
        __syncthreads();
        part[t] += x;
        __syncthreads();
    }
    if (t < NBKT) srcb_base[t] = part[t] - v;
    if (t == 0) srcb_base[NBKT] = N_EDGES;
}

// ---------------------------------------------------------------------------
// P3: scatter edges into bucket-partitioned arrays via LDS cursors.
__global__ __launch_bounds__(256) void p3_scatter(
    const int* __restrict__ src, const int* __restrict__ dst,
    const int* __restrict__ baseD, const int* __restrict__ baseS,
    const int* __restrict__ bucket_base, const int* __restrict__ srcb_base,
    unsigned int* __restrict__ edata, unsigned char* __restrict__ srcv) {
    __shared__ int curD[NBKT], curS[NBKT];
    int t = threadIdx.x, b = blockIdx.x;
    for (int i = t; i < NBKT; i += 256) {
        curD[i] = bucket_base[i] + baseD[b * NBKT + i];
        curS[i] = srcb_base[i] + baseS[b * NBKT + i];
    }
    __syncthreads();
    int e0 = b * EPB;
    for (int i = t; i < EPB; i += 256) {
        int s = src[e0 + i], d = dst[e0 + i];
        int slotD = atomicAdd(&curD[d >> 6], 1);
        edata[slotD] = (unsigned)s | ((unsigned)(d & 63) << 16);
        int slotS = atomicAdd(&curS[s >> 6], 1);
        srcv[slotS] = (unsigned char)(s & 63);
    }
}

// ---------------------------------------------------------------------------
// P4 fused: src-side count -> norm_src; dst-side count+scatter -> offsets,
// norm_dst, sorted_src (ushort: node ids < 65536). One block per bucket.
__global__ __launch_bounds__(256) void p4_fused(
    const int* __restrict__ srcb_base, const unsigned char* __restrict__ srcv,
    const int* __restrict__ bucket_base, const unsigned int* __restrict__ edata,
    int* __restrict__ offsets, float* __restrict__ norm_src,
    float* __restrict__ norm_dst, unsigned short* __restrict__ sorted_src) {
    __shared__ int cntS[64], cntD[64], cur[64];
    int t = threadIdx.x, b = blockIdx.x;
    if (t < 64) { cntS[t] = 0; cntD[t] = 0; }
    __syncthreads();
    int s0 = srcb_base[b], s1 = srcb_base[b + 1];
    for (int i = s0 + t; i < s1; i += 256) atomicAdd(&cntS[srcv[i]], 1);
    int d0 = bucket_base[b], d1 = bucket_base[b + 1];
    for (int i = d0 + t; i < d1; i += 256)
        atomicAdd(&cntD[(edata[i] >> 16) & 63], 1);
    __syncthreads();
    if (t == 0) {
        int run = 0;
        for (int i = 0; i < 64; i++) { cur[i] = run; run += cntD[i]; }
    }
    __syncthreads();
    if (t < 64) {
        int node = b * 64 + t;
        if (node < N_NODES) {
            norm_src[node] = rsqrtf(fmaxf((float)cntS[t], 1.0f));
            offsets[node] = d0 + cur[t];
            norm_dst[node] = rsqrtf(fmaxf((float)cntD[t], 1.0f));
        }
    }
    __syncthreads();
    for (int i = d0 + t; i < d1; i += 256) {
        unsigned e = edata[i];
        int slot = atomicAdd(&cur[(e >> 16) & 63], 1);
        sorted_src[d0 + slot] = (unsigned short)(e & 0xFFFFu);
    }
}

// ---------------------------------------------------------------------------
// agg1: one wave per dst node; per-edge norm_src fma (Hb is unscaled),
// 16 edges in flight (4 b128/lane), xor-16/32 butterfly, fused
// norm_dst+bias+relu, H1 out bf16 hi/lo with norm_src[wid] folded (for gemm2).
#define FMA8(W, NS)                                                   \
    acc0 = fmaf(__uint_as_float((W).x << 16), NS, acc0);              \
    acc1 = fmaf(__uint_as_float((W).x & 0xffff0000u), NS, acc1);      \
    acc2 = fmaf(__uint_as_float((W).y << 16), NS, acc2);              \
    acc3 = fmaf(__uint_as_float((W).y & 0xffff0000u), NS, acc3);      \
    acc4 = fmaf(__uint_as_float((W).z << 16), NS, acc4);              \
    acc5 = fmaf(__uint_as_float((W).z & 0xffff0000u), NS, acc5);      \
    acc6 = fmaf(__uint_as_float((W).w << 16), NS, acc6);              \
    acc7 = fmaf(__uint_as_float((W).w & 0xffff0000u), NS, acc7);

__global__ __launch_bounds__(256) void agg1_kernel(
    const int* __restrict__ offsets, const unsigned short* __restrict__ sorted_src,
    const unsigned short* __restrict__ Hb, const float* __restrict__ norm_dst,
    const float* __restrict__ norm_src, const float* __restrict__ b1,
    unsigned short* __restrict__ H1h, unsigned short* __restrict__ H1l) {
    int wid = (blockIdx.x * 256 + threadIdx.x) >> 6;
    int lane = threadIdx.x & 63;
    if (wid >= N_NODES) return;
    int start = offsets[wid], end = offsets[wid + 1];
    int quad = lane >> 4;
    int c8 = (lane & 15) * 8;
    float acc0 = 0.f, acc1 = 0.f, acc2 = 0.f, acc3 = 0.f;
    float acc4 = 0.f, acc5 = 0.f, acc6 = 0.f, acc7 = 0.f;
    int base = start;
    for (; base + 16 <= end; base += 16) {
        int e0 = sorted_src[base + quad];
        int e1 = sorted_src[base + 4 + quad];
        int e2 = sorted_src[base + 8 + quad];
        int e3 = sorted_src[base + 12 + quad];
        float n0 = norm_src[e0], n1 = norm_src[e1];
        float n2 = norm_src[e2], n3 = norm_src[e3];
        uint4 w0 = *(const uint4*)&Hb[(size_t)e0 * N_HIDDEN + c8];
        uint4 w1 = *(const uint4*)&Hb[(size_t)e1 * N_HIDDEN + c8];
        uint4 w2 = *(const uint4*)&Hb[(size_t)e2 * N_HIDDEN + c8];
        uint4 w3 = *(const uint4*)&Hb[(size_t)e3 * N_HIDDEN + c8];
        FMA8(w0, n0);
        FMA8(w1, n1);
        FMA8(w2, n2);
        FMA8(w3, n3);
    }
    for (; base + 4 <= end; base += 4) {
        int e = sorted_src[base + quad];
        float n = norm_src[e];
        uint4 w = *(const uint4*)&Hb[(size_t)e * N_HIDDEN + c8];
        FMA8(w, n);
    }
    int rem = end - base;
    if (quad < rem) {
        int e = sorted_src[base + quad];
        float n = norm_src[e];
        uint4 w = *(const uint4*)&Hb[(size_t)e * N_HIDDEN + c8];
        FMA8(w, n);
    }
    acc0 += __shfl_xor(acc0, 16); acc0 += __shfl_xor(acc0, 32);
    acc1 += __shfl_xor(acc1, 16); acc1 += __shfl_xor(acc1, 32);
    acc2 += __shfl_xor(acc2, 16); acc2 += __shfl_xor(acc2, 32);
    acc3 += __shfl_xor(acc3, 16); acc3 += __shfl_xor(acc3, 32);
    acc4 += __shfl_xor(acc4, 16); acc4 += __shfl_xor(acc4, 32);
    acc5 += __shfl_xor(acc5, 16); acc5 += __shfl_xor(acc5, 32);
    acc6 += __shfl_xor(acc6, 16); acc6 += __shfl_xor(acc6, 32);
    acc7 += __shfl_xor(acc7, 16); acc7 += __shfl_xor(acc7, 32);
    if (quad == 0) {
        float nd = norm_dst[wid];
        float ns = norm_src[wid];
        float4 ba = *(const float4*)&b1[c8];
        float4 bb = *(const float4*)&b1[c8 + 4];
        float o[8];
        o[0] = fmaxf(acc0 * nd + ba.x, 0.f) * ns;
        o[1] = fmaxf(acc1 * nd + ba.y, 0.f) * ns;
        o[2] = fmaxf(acc2 * nd + ba.z, 0.f) * ns;
        o[3] = fmaxf(acc3 * nd + ba.w, 0.f) * ns;
        o[4] = fmaxf(acc4 * nd + bb.x, 0.f) * ns;
        o[5] = fmaxf(acc5 * nd + bb.y, 0.f) * ns;
        o[6] = fmaxf(acc6 * nd + bb.z, 0.f) * ns;
        o[7] = fmaxf(acc7 * nd + bb.w, 0.f) * ns;
        unsigned short hh[8], ll[8];
#pragma unroll
        for (int t = 0; t < 8; t++) {
            hh[t] = f2bf(o[t]);
            ll[t] = f2bf(o[t] - bf2f(hh[t]));
        }
        uint4 ph = make_uint4((unsigned)hh[0] | ((unsigned)hh[1] << 16),
                              (unsigned)hh[2] | ((unsigned)hh[3] << 16),
                              (unsigned)hh[4] | ((unsigned)hh[5] << 16),
                              (unsigned)hh[6] | ((unsigned)hh[7] << 16));
        uint4 pl = make_uint4((unsigned)ll[0] | ((unsigned)ll[1] << 16),
                              (unsigned)ll[2] | ((unsigned)ll[3] << 16),
                              (unsigned)ll[4] | ((unsigned)ll[5] << 16),
                              (unsigned)ll[6] | ((unsigned)ll[7] << 16));
        *(uint4*)&H1h[(size_t)wid * N_HIDDEN + c8] = ph;
        *(uint4*)&H1l[(size_t)wid * N_HIDDEN + c8] = pl;
    }
}

// ---------------------------------------------------------------------------
// GEMM2 via bf16 MFMA: H2u[n][0:40] = H1n @ W2, PACKED hi|lo bf16 in u32
// (full f32 precision to 2^-17 rel), DENSE 40-dword rows (160B, 16B-aligned;
// c4*4 in {0,16,...,144} keeps uint4 alignment). -17% agg2 gather footprint
// vs the 48-stride layout.
__global__ __launch_bounds__(256) void gemm2_kernel(
    const unsigned short* __restrict__ H1h, const unsigned short* __restrict__ H1l,
    const unsigned short* __restrict__ W2th, const unsigned short* __restrict__ W2tl,
    unsigned int* __restrict__ H2u) {
    __shared__ __align__(16) unsigned short Bh[48][136];
    __shared__ __align__(16) unsigned short Bl[48][136];
    const int tid = threadIdx.x;
    for (int i = tid; i < 48 * 16; i += 256) {
        int n = i >> 4, kq = (i & 15) * 8;
        *(uint4*)&Bh[n][kq] = *(const uint4*)&W2th[n * 128 + kq];
        *(uint4*)&Bl[n][kq] = *(const uint4*)&W2tl[n * 128 + kq];
    }
    __syncthreads();
    const int lane = tid & 63;
    const int wave = tid >> 6;
    const int m = lane & 15;
    const int q = lane >> 4;
    const int row0 = blockIdx.x * 128 + wave * 32;

    f32x4 acc[2][3];
#pragma unroll
    for (int i = 0; i < 2; i++)
#pragma unroll
        for (int j = 0; j < 3; j++) acc[i][j] = (f32x4){0.f, 0.f, 0.f, 0.f};

#pragma unroll
    for (int kc = 0; kc < 4; kc++) {
        bf16x8 bh[3], bl[3];
#pragma unroll
        for (int j = 0; j < 3; j++) {
            bh[j] = *(const bf16x8*)&Bh[j * 16 + m][kc * 32 + q * 8];
            bl[j] = *(const bf16x8*)&Bl[j * 16 + m][kc * 32 + q * 8];
        }
#pragma unroll
        for (int i = 0; i < 2; i++) {
            size_t ro = (size_t)(row0 + i * 16 + m) * N_HIDDEN + kc * 32 + q * 8;
            bf16x8 ah = *(const bf16x8*)&H1h[ro];
            bf16x8 al = *(const bf16x8*)&H1l[ro];
#pragma unroll
            for (int j = 0; j < 3; j++) {
                acc[i][j] = __builtin_amdgcn_mfma_f32_16x16x32_bf16(ah, bh[j], acc[i][j], 0, 0, 0);
                acc[i][j] = __builtin_amdgcn_mfma_f32_16x16x32_bf16(ah, bl[j], acc[i][j], 0, 0, 0);
                acc[i][j] = __builtin_amdgcn_mfma_f32_16x16x32_bf16(al, bh[j], acc[i][j], 0, 0, 0);
            }
        }
    }
#pragma unroll
    for (int i = 0; i < 2; i++) {
#pragma unroll
        for (int r = 0; r < 4; r++) {
            int row = row0 + i * 16 + q * 4 + r;
            if (row < N_NODES) {
#pragma unroll
                for (int j = 0; j < 3; j++) {
                    int col = j * 16 + m;
                    if (col < N_CLASSES) {
                        float v = acc[i][j][r];
                        unsigned short h = f2bf(v);
                        unsigned short l = f2bf(v - bf2f(h));
                        H2u[(size_t)row * 40 + col] = ((unsigned)h << 16) | (unsigned)l;
                    }
                }
            }
        }
    }
}

// ---------------------------------------------------------------------------
// agg2: one wave per dst node; 16 edges in flight (4 uint4/lane), packed
// hi|lo bf16 reconstruction, butterfly reduce. H2u dense stride 40.
#define ACC4(V)                                                               \
    acc.x += __uint_as_float((V).x & 0xffff0000u) + __uint_as_float((V).x << 16); \
    acc.y += __uint_as_float((V).y & 0xffff0000u) + __uint_as_float((V).y << 16); \
    acc.z += __uint_as_float((V).z & 0xffff0000u) + __uint_as_float((V).z << 16); \
    acc.w += __uint_as_float((V).w & 0xffff0000u) + __uint_as_float((V).w << 16);

__global__ __launch_bounds__(256) void agg2_kernel(
    const int* __restrict__ offsets, const unsigned short* __restrict__ sorted_src,
    const unsigned int* __restrict__ H2u, const float* __restrict__ norm_dst,
    const float* __restrict__ b2, float* __restrict__ OUT) {
    int wid = (blockIdx.x * 256 + threadIdx.x) >> 6;
    int lane = threadIdx.x & 63;
    if (wid >= N_NODES) return;
    int start = offsets[wid], end = offsets[wid + 1];
    int quad = lane >> 4;
    int c4 = (lane & 15) * 4;
    bool active = c4 < N_CLASSES;
    float4 acc = make_float4(0.f, 0.f, 0.f, 0.f);
    int base = start;
    for (; base + 16 <= end; base += 16) {
        int e0 = sorted_src[base + quad];
        int e1 = sorted_src[base + 4 + quad];
        int e2 = sorted_src[base + 8 + quad];
        int e3 = sorted_src[base + 12 + quad];
        if (active) {
            uint4 v0 = *(const uint4*)&H2u[(size_t)e0 * 40 + c4];
            uint4 v1 = *(const uint4*)&H2u[(size_t)e1 * 40 + c4];
            uint4 v2 = *(const uint4*)&H2u[(size_t)e2 * 40 + c4];
            uint4 v3 = *(const uint4*)&H2u[(size_t)e3 * 40 + c4];
            ACC4(v0); ACC4(v1); ACC4(v2); ACC4(v3);
        }
    }
    for (; base + 4 <= end; base += 4) {
        int e = sorted_src[base + quad];
        if (active) {
            uint4 v = *(const uint4*)&H2u[(size_t)e * 40 + c4];
            ACC4(v);
        }
    }
    int rem = end - base;
    if (quad < rem && active) {
        int e = sorted_src[base + quad];
        uint4 v = *(const uint4*)&H2u[(size_t)e * 40 + c4];
        ACC4(v);
    }
    acc.x += __shfl_xor(acc.x, 16); acc.x += __shfl_xor(acc.x, 32);
    acc.y += __shfl_xor(acc.y, 16); acc.y += __shfl_xor(acc.y, 32);
    acc.z += __shfl_xor(acc.z, 16); acc.z += __shfl_xor(acc.z, 32);
    acc.w += __shfl_xor(acc.w, 16); acc.w += __shfl_xor(acc.w, 32);
    if (lane < 10) {
        float nd = norm_dst[wid];
        float4 b = *(const float4*)&b2[lane * 4];
        acc.x = acc.x * nd + b.x;
        acc.y = acc.y * nd + b.y;
        acc.z = acc.z * nd + b.z;
        acc.w = acc.w * nd + b.w;
        *(float4*)&OUT[(size_t)wid * N_CLASSES + lane * 4] = acc;
    }
}

// ---------------------------------------------------------------------------
extern "C" void kernel_launch(void* const* d_in, const int* in_sizes, int n_in,
                              void* d_out, int out_size, void* d_ws, size_t ws_size,
                              hipStream_t stream) {
    const float* X   = (const float*)d_in[0];
    const float* W1  = (const float*)d_in[1];
    const float* b1  = (const float*)d_in[2];
    const float* W2  = (const float*)d_in[3];
    const float* b2  = (const float*)d_in[4];
    const int*   src = (const int*)d_in[5];
    const int*   dst = (const int*)d_in[6];
    float* out = (float*)d_out;

    // workspace layout (4B units). regionA time-shared:
    //   phase 1: histD|histS|baseD|baseS|totD|totS      [dead after p3]
    //   phase 3: H2u packed u32 50000x40 (2M dwords)    [written at gemm2]
    // Hb has its own region (written by megaA while phase-1 data live).
    float* norm_src   = (float*)d_ws;                     // 50000
    float* norm_dst   = norm_src + N_NODES;               // 50000
    int*   offsets    = (int*)(norm_dst + N_NODES);       // 50016 (incl pad)
    int*   bucket_base = offsets + N_NODES + 16;          // 800
    int*   srcb_base  = bucket_base + 800;                // 800
    unsigned int* edata = (unsigned int*)(srcb_base + 800);       // 1.6M
    unsigned char* srcv = (unsigned char*)(edata + N_EDGES);      // 400K dwords
    unsigned short* sorted_src =
        (unsigned short*)((int*)(edata + N_EDGES) + 400000);      // 1.6M ushort
    int*   regionA    = (int*)(edata + N_EDGES) + 400000 + 800000; // 3.2M dwords
    int*   histD      = regionA;
    int*   histS      = regionA + 625600;
    int*   baseD      = regionA + 1251200;
    int*   baseS      = regionA + 1876800;
    int*   totD       = regionA + 2502400;                // 800
    int*   totS       = regionA + 2503200;                // 800
    unsigned int* H2u = (unsigned int*)regionA;           // phase 3 (2M)
    unsigned short* H1h = (unsigned short*)(regionA + 3200000);   // 50048x128 bf16
    unsigned short* H1l = H1h + (size_t)NROWPAD * N_HIDDEN;
    unsigned short* W1ch = H1l + (size_t)NROWPAD * N_HIDDEN;      // k-chunked 512*128
    unsigned short* W1cl = W1ch + IN_FEATS * N_HIDDEN;
    unsigned short* W2th = W1cl + IN_FEATS * N_HIDDEN;            // 48*128
    unsigned short* W2tl = W2th + 48 * 128;
    unsigned short* Hb   = W2tl + 48 * 128;               // 50000x128 bf16 (own region)

    setup_cvt<<<(IN_FEATS * N_HIDDEN + 48 * 128) / 256, 256, 0, stream>>>(
        W1, W2, W1ch, W1cl, W2th, W2tl);
    megaA<<<NBLK + NBKT, 256, 0, stream>>>(src, dst, histD, histS, X, W1ch, W1cl, Hb);
    p2_local<<<(NBKT + 3) / 4, 256, 0, stream>>>(histD, histS, baseD, baseS, totD, totS);
    p2_small<<<1, 1024, 0, stream>>>(totD, totS, bucket_base, srcb_base, offsets);
    p3_scatter<<<NBLK, 256, 0, stream>>>(src, dst, baseD, baseS, bucket_base, srcb_base,
                                         edata, srcv);
    p4_fused<<<NBKT, 256, 0, stream>>>(srcb_base, srcv, bucket_base, edata,
                                       offsets, norm_src, norm_dst, sorted_src);
    agg1_kernel<<<(N_NODES + 3) / 4, 256, 0, stream>>>(offsets, sorted_src, Hb, norm_dst,
                                                       norm_src, b1, H1h, H1l);
    gemm2_kernel<<<(N_NODES + 127) / 128, 256, 0, stream>>>(H1h, H1l, W2th, W2tl, H2u);
    agg2_kernel<<<(N_NODES + 3) / 4, 256, 0, stream>>>(offsets, sorted_src, H2u, norm_dst, b2, out);
}